// Round 5
// baseline (367.279 us; speedup 1.0000x reference)
//
#include <hip/hip_runtime.h>
#include <hip/hip_bf16.h>
#include <math.h>

#define TID threadIdx.x

constexpr int Cc = 512, Tt = 1024, C3 = 1536;

typedef __attribute__((ext_vector_type(8))) __bf16 bf16x8;
typedef __attribute__((ext_vector_type(4))) float f32x4;

__device__ __forceinline__ void async16(const void* g, void* l) {
  __builtin_amdgcn_global_load_lds(
      (const __attribute__((address_space(1))) unsigned int*)g,
      (__attribute__((address_space(3))) unsigned int*)l, 16, 0, 0);
}

__device__ __forceinline__ unsigned int pack2bf(float a, float b) {
  __hip_bfloat162 h;
  h.x = __float2bfloat16(a);
  h.y = __float2bfloat16(b);
  return *reinterpret_cast<unsigned int*>(&h);
}

__device__ __forceinline__ float mishf(float x) {
  float sp = (x > 20.f) ? x : log1pf(__expf(x));
  return x * tanhf(sp);
}

__device__ __forceinline__ void blockReduce2(float& s, float& ss) {
  #pragma unroll
  for (int off = 32; off > 0; off >>= 1) {
    s  += __shfl_xor(s,  off);
    ss += __shfl_xor(ss, off);
  }
  __shared__ float ls[4], lss[4];
  int w = TID >> 6;
  if ((TID & 63) == 0) { ls[w] = s; lss[w] = ss; }
  __syncthreads();
  s  = ls[0] + ls[1] + ls[2] + ls[3];
  ss = lss[0] + lss[1] + lss[2] + lss[3];
}

// ---------------- fused GN(32) + im2col(K=2, pad_lo=0) -> bf16 B1t[b][t][k=2ci+j] ----------------
__global__ __launch_bounds__(256) void gn1_im2col(const float* __restrict__ x,
    const float* __restrict__ w, const float* __restrict__ bv,
    __hip_bfloat16* __restrict__ B1t) {
  __shared__ float hs[16][262];
  int blk = blockIdx.x, bb = blk >> 5, g = blk & 31;
  size_t base = ((size_t)bb * Cc + g * 16) * Tt;
  const float* xp = x + base;
  float s = 0.f, ss = 0.f;
  for (int i = TID * 4; i < 16 * Tt; i += 1024) {
    float4 v = *reinterpret_cast<const float4*>(xp + i);
    s  += v.x + v.y + v.z + v.w;
    ss += v.x * v.x + v.y * v.y + v.z * v.z + v.w * v.w;
  }
  blockReduce2(s, ss);
  float mean = s * (1.f / 16384.f);
  float rstd = rsqrtf(ss * (1.f / 16384.f) - mean * mean + 1e-5f);

  char* ob = reinterpret_cast<char*>(B1t + (size_t)bb * Tt * 1024 + g * 32);
  for (int tc = 0; tc < 4; ++tc) {
    int tbase = tc * 256;
    __syncthreads();
    for (int task = TID; task < 1024; task += 256) {
      int row = task >> 6, c4 = task & 63;
      int ch = g * 16 + row;
      float sw = w[ch] * rstd;
      float sb = bv[ch] - mean * sw;
      float4 v = *reinterpret_cast<const float4*>(xp + (size_t)row * Tt + tbase + c4 * 4);
      hs[row][c4 * 4 + 0] = v.x * sw + sb;
      hs[row][c4 * 4 + 1] = v.y * sw + sb;
      hs[row][c4 * 4 + 2] = v.z * sw + sb;
      hs[row][c4 * 4 + 3] = v.w * sw + sb;
    }
    if (TID < 16) {
      int row = TID, t = tbase + 256;
      float val = 0.f;
      if (t < Tt) {
        int ch = g * 16 + row;
        float sw = w[ch] * rstd;
        float sb = bv[ch] - mean * sw;
        val = xp[(size_t)row * Tt + t] * sw + sb;
      }
      hs[row][256] = val;
    }
    __syncthreads();
    for (int task = TID; task < 1024; task += 256) {
      int t = task >> 2, cj = task & 3;
      int ci = cj * 4;
      uint4 u;
      u.x = pack2bf(hs[ci + 0][t], hs[ci + 0][t + 1]);
      u.y = pack2bf(hs[ci + 1][t], hs[ci + 1][t + 1]);
      u.z = pack2bf(hs[ci + 2][t], hs[ci + 2][t + 1]);
      u.w = pack2bf(hs[ci + 3][t], hs[ci + 3][t + 1]);
      *reinterpret_cast<uint4*>(ob + ((size_t)(tbase + t) * 1024 + cj * 8) * 2) = u;
    }
  }
}

// ---------------- im2col(K=4, pad_lo=1) on attn output -> bf16 B4t[b][t][k=4ci+j], coalesced ----------------
__global__ __launch_bounds__(256) void im2col_k4(const float* __restrict__ a,
    __hip_bfloat16* __restrict__ B4t) {
  __shared__ float hs[16][266];
  int bb = blockIdx.x >> 5, cg = blockIdx.x & 31;
  const float* ab = a + ((size_t)bb * Cc + cg * 16) * Tt;
  char* ob = reinterpret_cast<char*>(B4t + (size_t)bb * Tt * 2048 + cg * 64);
  for (int tc = 0; tc < 4; ++tc) {
    int tbase = tc * 256;
    __syncthreads();
    for (int task = TID; task < 1024; task += 256) {
      int row = task >> 6, c4 = task & 63;
      float4 v = *reinterpret_cast<const float4*>(ab + (size_t)row * Tt + tbase + c4 * 4);
      hs[row][c4 * 4 + 1] = v.x;
      hs[row][c4 * 4 + 2] = v.y;
      hs[row][c4 * 4 + 3] = v.z;
      hs[row][c4 * 4 + 4] = v.w;
    }
    if (TID < 48) {
      int row = TID / 3, e = TID % 3;
      int t = (e == 0) ? tbase - 1 : tbase + 256 + (e - 1);
      float v = (t >= 0 && t < Tt) ? ab[(size_t)row * Tt + t] : 0.f;
      int col = (e == 0) ? 0 : 257 + (e - 1);
      hs[row][col] = v;
    }
    __syncthreads();
    for (int task = TID; task < 2048; task += 256) {
      int t = task >> 3, cj = task & 7;
      int ci = cj * 2;
      uint4 u;
      u.x = pack2bf(hs[ci][t],     hs[ci][t + 1]);
      u.y = pack2bf(hs[ci][t + 2], hs[ci][t + 3]);
      u.z = pack2bf(hs[ci + 1][t],     hs[ci + 1][t + 1]);
      u.w = pack2bf(hs[ci + 1][t + 2], hs[ci + 1][t + 3]);
      *reinterpret_cast<uint4*>(ob + ((size_t)(tbase + t) * 2048 + cj * 8) * 2) = u;
    }
  }
}

// ---------------- f32 -> bf16 cast (weights) ----------------
__global__ __launch_bounds__(256) void cast_bf16(const float* __restrict__ in,
    __hip_bfloat16* __restrict__ out, int n) {
  int i = (blockIdx.x * 256 + TID) * 4;
  if (i >= n) return;
  float4 v = *reinterpret_cast<const float4*>(in + i);
  *reinterpret_cast<unsigned int*>(out + i)     = pack2bf(v.x, v.y);
  *reinterpret_cast<unsigned int*>(out + i + 2) = pack2bf(v.z, v.w);
}

// ---------------- bf16 MFMA GEMM v2: prefetch double-buffered (T3-minimum) ----------------
// C[b][o][t] = sum_k A[o][k] * Bt[b][t][k] + bias[o].  BK=32, 4 waves in 2x2 grid.
// LDS: 2 buffers of CH 1KB chunks (chunk = 16 rows x 32 k, lane-ordered).
template<int K, int MT, int NT>
__global__ __launch_bounds__(256) void gemm_bt2(const __hip_bfloat16* __restrict__ A,
    const __hip_bfloat16* __restrict__ Bt, const float* __restrict__ bias,
    float* __restrict__ C, int M) {
  constexpr int MF = MT / 16, NFr = NT / 16;
  constexpr int CH = MF + NFr;
  constexpr int MW = MF / 2, NW = NFr / 2;
  constexpr int NKT = K / 32;
  __shared__ __align__(16) char lds[2 * CH * 1024];
  int t0 = blockIdx.x * NT, o0 = blockIdx.y * MT, bz = blockIdx.z;
  int wave = TID >> 6, lane = TID & 63;
  int l4 = lane >> 4, r15 = lane & 15;
  int wm = wave >> 1, wn = wave & 1;
  const __hip_bfloat16* aBase = A + ((size_t)o0 + r15) * K + l4 * 8;
  const __hip_bfloat16* bBase = Bt + ((size_t)bz * 1024 + t0 + r15) * K + l4 * 8;

  f32x4 acc[MW][NW];
  f32x4 zz = {0.f, 0.f, 0.f, 0.f};
  #pragma unroll
  for (int m = 0; m < MW; ++m)
    #pragma unroll
    for (int n = 0; n < NW; ++n) acc[m][n] = zz;

  auto stage = [&](int kt, int buf) {
    char* dst = lds + buf * (CH * 1024);
    #pragma unroll
    for (int c = 0; c < CH / 4; ++c) {
      int ch = c * 4 + wave;
      const __hip_bfloat16* src = (ch < MF)
          ? (aBase + (size_t)ch * 16 * K + kt * 32)
          : (bBase + (size_t)(ch - MF) * 16 * K + kt * 32);
      async16(src, dst + ch * 1024 + lane * 16);
    }
  };

  stage(0, 0);
  __syncthreads();
  for (int kt = 0; kt < NKT; ++kt) {
    if (kt + 1 < NKT) stage(kt + 1, (kt + 1) & 1);
    char* cur = lds + (kt & 1) * (CH * 1024);
    bf16x8 af[MW], bfr[NW];
    #pragma unroll
    for (int m = 0; m < MW; ++m)
      af[m] = *reinterpret_cast<const bf16x8*>(cur + (wm * MW + m) * 1024 + lane * 16);
    #pragma unroll
    for (int n = 0; n < NW; ++n)
      bfr[n] = *reinterpret_cast<const bf16x8*>(cur + (MF + wn * NW + n) * 1024 + lane * 16);
    #pragma unroll
    for (int m = 0; m < MW; ++m)
      #pragma unroll
      for (int n = 0; n < NW; ++n)
        acc[m][n] = __builtin_amdgcn_mfma_f32_16x16x32_bf16(af[m], bfr[n], acc[m][n], 0, 0, 0);
    if (kt + 1 < NKT) __syncthreads();
  }

  #pragma unroll
  for (int m = 0; m < MW; ++m)
    #pragma unroll
    for (int n = 0; n < NW; ++n) {
      int ocol = t0 + (wn * NW + n) * 16 + r15;
      #pragma unroll
      for (int r = 0; r < 4; ++r) {
        int orow = o0 + (wm * MW + m) * 16 + l4 * 4 + r;
        C[((size_t)bz * M + orow) * 1024 + ocol] = acc[m][n][r] + bias[orow];
      }
    }
}

// ---------------- generic GroupNorm stats ----------------
__global__ __launch_bounds__(256) void gn_stats_kernel(const float* __restrict__ x,
    float2* __restrict__ stats, int n) {
  const float* p = x + (size_t)blockIdx.x * n;
  float s = 0.f, ss = 0.f;
  for (int i = TID * 4; i < n; i += 1024) {
    float4 v = *reinterpret_cast<const float4*>(p + i);
    s  += v.x + v.y + v.z + v.w;
    ss += v.x * v.x + v.y * v.y + v.z * v.z + v.w * v.w;
  }
  blockReduce2(s, ss);
  if (TID == 0) {
    float mean = s / (float)n;
    float var = ss / (float)n - mean * mean;
    stats[blockIdx.x] = make_float2(mean, rsqrtf(var + 1e-5f));
  }
}

// ---------------- fused GN(8)+Mish + build attn input images ----------------
__global__ __launch_bounds__(256) void gn2_prep(const float* __restrict__ qkv,
    const float2* __restrict__ st, const float* __restrict__ w, const float* __restrict__ bv,
    char* __restrict__ qTp, char* __restrict__ kimg, char* __restrict__ vimg) {
  __shared__ unsigned short hbf[192 * 66];
  int tl = blockIdx.x & 15, hb = blockIdx.x >> 4;
  int b = hb >> 3, hd = hb & 7;
  const float* base = qkv + ((size_t)b * C3 + hd * 192) * Tt + tl * 64;
  float2 ms = st[b * 8 + hd];
  for (int task = TID; task < 768; task += 256) {
    int row = task >> 2, seg = task & 3;
    int ch = hd * 192 + row;
    float sw = w[ch] * ms.y;
    float sb = bv[ch] - ms.x * sw;
    const float* src = base + (size_t)row * Tt + seg * 16;
    unsigned int* dst = reinterpret_cast<unsigned int*>(&hbf[row * 66 + seg * 16]);
    #pragma unroll
    for (int q4 = 0; q4 < 4; ++q4) {
      float4 v = *reinterpret_cast<const float4*>(src + q4 * 4);
      dst[q4 * 2]     = pack2bf(mishf(v.x * sw + sb), mishf(v.y * sw + sb));
      dst[q4 * 2 + 1] = pack2bf(mishf(v.z * sw + sb), mishf(v.w * sw + sb));
    }
  }
  __syncthreads();
  size_t tileof = ((size_t)hb * 16 + tl) * 8192;
  {
    int t = TID & 63, sel = TID >> 6;
    int img = sel >> 1, half = sel & 1;
    char* obase = (img == 0 ? qTp : kimg) + tileof + (size_t)t * 128;
    #pragma unroll
    for (int cc = 0; cc < 4; ++cc) {
      int chunk = half * 4 + cc;
      uint4 u;
      unsigned int* up = reinterpret_cast<unsigned int*>(&u);
      #pragma unroll
      for (int j = 0; j < 4; ++j) {
        int c = chunk * 8 + j * 2;
        unsigned int lo = hbf[(img * 64 + c) * 66 + t];
        unsigned int hi = hbf[(img * 64 + c + 1) * 66 + t];
        up[j] = lo | (hi << 16);
      }
      int cpos = (img == 0) ? chunk : (chunk ^ (t & 7));
      *reinterpret_cast<uint4*>(obase + cpos * 16) = u;
    }
  }
  {
    int c = TID & 63, qtr = TID >> 6;
    const unsigned int* vrow = reinterpret_cast<const unsigned int*>(&hbf[(128 + c) * 66]);
    char* obase = vimg + tileof + (size_t)c * 128;
    #pragma unroll
    for (int k = 0; k < 2; ++k) {
      int chunk = qtr * 2 + k;
      uint4 u;
      unsigned int* up = reinterpret_cast<unsigned int*>(&u);
      #pragma unroll
      for (int j = 0; j < 4; ++j) up[j] = vrow[chunk * 4 + j];
      *reinterpret_cast<uint4*>(obase + (chunk ^ (c & 7)) * 16) = u;
    }
  }
}

// ---------------- MFMA flash attention v2: async-staged images, double-buffered ----------------
__global__ __launch_bounds__(256) void attn_mfma2(const char* __restrict__ qTp,
    const char* __restrict__ kimg, const char* __restrict__ vimg,
    float* __restrict__ a) {
  __shared__ __align__(16) char smem[40960];
  char* kbuf0 = smem;
  char* kbuf1 = smem + 8192;
  char* vbuf0 = smem + 16384;
  char* vbuf1 = smem + 24576;
  char* pp    = smem + 32768;
  char* ov    = smem;

  int tl = blockIdx.x, hb = blockIdx.y;
  int b = hb >> 3, hd = hb & 7;
  int lane = TID & 63, wave = TID >> 6;
  int l4 = lane >> 4, r15 = lane & 15;
  size_t ibase = (size_t)hb * 16 * 8192;
  const char* ksrc = kimg + ibase;
  const char* vsrc = vimg + ibase;

  #pragma unroll
  for (int j = 0; j < 2; ++j) {
    int u = j * 256 + TID;
    async16(ksrc + u * 16, kbuf0 + u * 16);
    async16(vsrc + u * 16, vbuf0 + u * 16);
  }
  bf16x8 aq[2];
  int tg = wave * 16 + r15;
  const char* qrow = qTp + ibase + (size_t)tl * 8192 + (size_t)tg * 128;
  aq[0] = *reinterpret_cast<const bf16x8*>(qrow + l4 * 16);
  aq[1] = *reinterpret_cast<const bf16x8*>(qrow + 64 + l4 * 16);

  f32x4 osum[4];
  f32x4 zz = {0.f, 0.f, 0.f, 0.f};
  #pragma unroll
  for (int cf = 0; cf < 4; ++cf) osum[cf] = zz;
  float mrow[4] = {-1e30f, -1e30f, -1e30f, -1e30f};
  float lrow[4] = {0.f, 0.f, 0.f, 0.f};
  __syncthreads();

  for (int it = 0; it < 16; ++it) {
    char* kcur = (it & 1) ? kbuf1 : kbuf0;
    char* vcur = (it & 1) ? vbuf1 : vbuf0;
    if (it < 15) {
      char* knxt = (it & 1) ? kbuf0 : kbuf1;
      char* vnxt = (it & 1) ? vbuf0 : vbuf1;
      const char* kn = ksrc + (size_t)(it + 1) * 8192;
      const char* vn = vsrc + (size_t)(it + 1) * 8192;
      #pragma unroll
      for (int j = 0; j < 2; ++j) {
        int u = j * 256 + TID;
        async16(kn + u * 16, knxt + u * 16);
        async16(vn + u * 16, vnxt + u * 16);
      }
    }
    f32x4 sc[4];
    #pragma unroll
    for (int sf = 0; sf < 4; ++sf) sc[sf] = zz;
    #pragma unroll
    for (int sf = 0; sf < 4; ++sf) {
      int sr = sf * 16 + r15;
      #pragma unroll
      for (int kk = 0; kk < 2; ++kk) {
        bf16x8 bk = *reinterpret_cast<const bf16x8*>(kcur + sr * 128 + (((kk * 4 + l4) ^ (sr & 7)) << 4));
        sc[sf] = __builtin_amdgcn_mfma_f32_16x16x32_bf16(aq[kk], bk, sc[sf], 0, 0, 0);
      }
    }
    float tmax[4];
    #pragma unroll
    for (int r = 0; r < 4; ++r)
      tmax[r] = fmaxf(fmaxf(sc[0][r], sc[1][r]), fmaxf(sc[2][r], sc[3][r]));
    #pragma unroll
    for (int off = 1; off < 16; off <<= 1)
      #pragma unroll
      for (int r = 0; r < 4; ++r) tmax[r] = fmaxf(tmax[r], __shfl_xor(tmax[r], off));
    float alpha[4];
    #pragma unroll
    for (int r = 0; r < 4; ++r) {
      float mnew = fmaxf(mrow[r], tmax[r]);
      alpha[r] = __expf((mrow[r] - mnew) * 0.125f);
      mrow[r] = mnew;
      lrow[r] *= alpha[r];
    }
    #pragma unroll
    for (int cf = 0; cf < 4; ++cf)
      #pragma unroll
      for (int r = 0; r < 4; ++r) osum[cf][r] *= alpha[r];
    char* pw = pp + wave * 2048;
    float psum[4] = {0.f, 0.f, 0.f, 0.f};
    #pragma unroll
    for (int sf = 0; sf < 4; ++sf) {
      int s = sf * 16 + r15;
      #pragma unroll
      for (int r = 0; r < 4; ++r) {
        float p = __expf((sc[sf][r] - mrow[r]) * 0.125f);
        psum[r] += p;
        int tlc = l4 * 4 + r;
        *reinterpret_cast<__hip_bfloat16*>(pw + tlc * 128 + ((((s >> 3) ^ (tlc & 7)) << 4) | ((s & 7) * 2)))
            = __float2bfloat16(p);
      }
    }
    #pragma unroll
    for (int r = 0; r < 4; ++r) lrow[r] += psum[r];
    asm volatile("s_waitcnt lgkmcnt(0)" ::: "memory");
    __builtin_amdgcn_sched_barrier(0);

    bf16x8 pa[2];
    #pragma unroll
    for (int kk = 0; kk < 2; ++kk)
      pa[kk] = *reinterpret_cast<const bf16x8*>(pw + r15 * 128 + (((kk * 4 + l4) ^ (r15 & 7)) << 4));
    #pragma unroll
    for (int cf = 0; cf < 4; ++cf) {
      int cr = cf * 16 + r15;
      #pragma unroll
      for (int kk = 0; kk < 2; ++kk) {
        bf16x8 bv = *reinterpret_cast<const bf16x8*>(vcur + cr * 128 + (((kk * 4 + l4) ^ (cr & 7)) << 4));
        osum[cf] = __builtin_amdgcn_mfma_f32_16x16x32_bf16(pa[kk], bv, osum[cf], 0, 0, 0);
      }
    }
    __syncthreads();
  }

  #pragma unroll
  for (int off = 1; off < 16; off <<= 1)
    #pragma unroll
    for (int r = 0; r < 4; ++r) lrow[r] += __shfl_xor(lrow[r], off);
  float linv[4];
  #pragma unroll
  for (int r = 0; r < 4; ++r) linv[r] = 1.f / lrow[r];

  #pragma unroll
  for (int cf = 0; cf < 4; ++cf) {
    int c = cf * 16 + r15;
    #pragma unroll
    for (int r = 0; r < 4; ++r) {
      int t = wave * 16 + l4 * 4 + r;
      *reinterpret_cast<float*>(ov + c * 256 + ((((t >> 2) ^ (c & 7)) << 4) | ((t & 3) * 4)))
          = osum[cf][r] * linv[r];
    }
  }
  __syncthreads();
  float* ap = a + ((size_t)b * Cc + hd * 64) * Tt + tl * 64;
  for (int u = TID; u < 1024; u += 256) {
    int c = u >> 4, tq = u & 15;
    float4 o4 = *reinterpret_cast<const float4*>(ov + c * 256 + ((tq ^ (c & 7)) << 4));
    *reinterpret_cast<float4*>(ap + (size_t)c * Tt + tq * 4) = o4;
  }
}

// ---------------- final: out = x + mish(gn(y2)) in-place on d_out ----------------
__global__ __launch_bounds__(256) void final_kernel(const float* __restrict__ x,
    float* __restrict__ y, const float2* __restrict__ st,
    const float* __restrict__ w, const float* __restrict__ bv) {
  size_t i = ((size_t)blockIdx.x * 256 + TID) * 4;
  int ch = (int)((i >> 10) & (Cc - 1));
  int b = (int)(i >> 19);
  float2 ms = st[b * 8 + (ch >> 6)];
  float sw = w[ch] * ms.y;
  float sb = bv[ch] - ms.x * sw;
  float4 v  = *reinterpret_cast<const float4*>(y + i);
  float4 xv = *reinterpret_cast<const float4*>(x + i);
  v.x = xv.x + mishf(v.x * sw + sb);
  v.y = xv.y + mishf(v.y * sw + sb);
  v.z = xv.z + mishf(v.z * sw + sb);
  v.w = xv.w + mishf(v.w * sw + sb);
  *reinterpret_cast<float4*>(y + i) = v;
}

extern "C" void kernel_launch(void* const* d_in, const int* in_sizes, int n_in,
                              void* d_out, int out_size, void* d_ws, size_t ws_size,
                              hipStream_t stream) {
  const float* x     = (const float*)d_in[0];
  const float* gn_w  = (const float*)d_in[1];
  const float* gn_b  = (const float*)d_in[2];
  const float* wqkv  = (const float*)d_in[3];
  const float* bqkv  = (const float*)d_in[4];
  const float* gnq_w = (const float*)d_in[5];
  const float* gnq_b = (const float*)d_in[6];
  const float* wproj = (const float*)d_in[7];
  const float* bproj = (const float*)d_in[8];
  const float* gnp_w = (const float*)d_in[9];
  const float* gnp_b = (const float*)d_in[10];
  float* out = (float*)d_out;

  char* ws = (char*)d_ws;
  const size_t MB = 1024 * 1024;
  float* qkv = (float*)ws;                               // [0,48MB)   step3 -> step5
  float* hbuf = (float*)ws;                              // [0,16MB)   step6 -> step7 (qkv dead)
  __hip_bfloat16* B4t = (__hip_bfloat16*)(ws + 16 * MB); // [16,48MB)  step7 -> step9
  __hip_bfloat16* A1  = (__hip_bfloat16*)(ws + 48 * MB); // [48,51MB)  step1 -> step3
  char* vimg = ws + 48 * MB;                             // [48,56MB)  step5 -> step6 (A1 dead)
  __hip_bfloat16* A2  = (__hip_bfloat16*)(ws + 48 * MB); // [48,50MB)  step8 -> step9 (vimg dead)
  float2* st2 = (float2*)(ws + 63 * MB);
  float2* st3 = st2 + 64;
  __hip_bfloat16* B1t = (__hip_bfloat16*)d_out;          // d_out as B1t  step2 -> step3
  char* qTp  = (char*)d_out;                             // d_out[0,8MB)  step5 -> step6
  char* kimg = (char*)d_out + 8 * MB;                    // d_out[8,16MB) step5 -> step6

  dim3 blk(256);
  cast_bf16<<<1536, blk, 0, stream>>>(wqkv, A1, C3 * 1024);                        // 1
  gn1_im2col<<<256, blk, 0, stream>>>(x, gn_w, gn_b, B1t);                         // 2
  gemm_bt2<1024, 64, 128><<<dim3(8, 24, 8), blk, 0, stream>>>(A1, B1t, bqkv, qkv, C3); // 3
  gn_stats_kernel<<<64, blk, 0, stream>>>(qkv, st2, 192 * 1024);                   // 4
  gn2_prep<<<1024, blk, 0, stream>>>(qkv, st2, gnq_w, gnq_b, qTp, kimg, vimg);     // 5
  attn_mfma2<<<dim3(16, 64), blk, 0, stream>>>(qTp, kimg, vimg, hbuf);             // 6
  im2col_k4<<<256, blk, 0, stream>>>(hbuf, B4t);                                   // 7
  cast_bf16<<<1024, blk, 0, stream>>>(wproj, A2, Cc * 2048);                       // 8
  gemm_bt2<2048, 64, 64><<<dim3(16, 8, 8), blk, 0, stream>>>(A2, B4t, bproj, out, Cc); // 9
  gn_stats_kernel<<<64, blk, 0, stream>>>(out, st3, 64 * 1024);                    // 10
  final_kernel<<<4096, blk, 0, stream>>>(x, out, st3, gnp_w, gnp_b);               // 11
}

// Round 6
// 365.618 us; speedup vs baseline: 1.0045x; 1.0045x over previous
//
#include <hip/hip_runtime.h>
#include <hip/hip_bf16.h>
#include <math.h>

#define TID threadIdx.x

constexpr int Cc = 512, Tt = 1024, C3 = 1536;

typedef __attribute__((ext_vector_type(8))) __bf16 bf16x8;
typedef __attribute__((ext_vector_type(4))) float f32x4;

__device__ __forceinline__ void async16(const void* g, void* l) {
  __builtin_amdgcn_global_load_lds(
      (const __attribute__((address_space(1))) unsigned int*)g,
      (__attribute__((address_space(3))) unsigned int*)l, 16, 0, 0);
}

template<int N> __device__ __forceinline__ void wait_vmcnt() {
  asm volatile("s_waitcnt vmcnt(%0)" :: "n"(N) : "memory");
}

__device__ __forceinline__ unsigned int pack2bf(float a, float b) {
  __hip_bfloat162 h;
  h.x = __float2bfloat16(a);
  h.y = __float2bfloat16(b);
  return *reinterpret_cast<unsigned int*>(&h);
}

__device__ __forceinline__ float mishf(float x) {
  float sp = (x > 20.f) ? x : log1pf(__expf(x));
  return x * tanhf(sp);
}

__device__ __forceinline__ void blockReduce2(float& s, float& ss) {
  #pragma unroll
  for (int off = 32; off > 0; off >>= 1) {
    s  += __shfl_xor(s,  off);
    ss += __shfl_xor(ss, off);
  }
  __shared__ float ls[4], lss[4];
  int w = TID >> 6;
  if ((TID & 63) == 0) { ls[w] = s; lss[w] = ss; }
  __syncthreads();
  s  = ls[0] + ls[1] + ls[2] + ls[3];
  ss = lss[0] + lss[1] + lss[2] + lss[3];
}

// ---------------- fused GN(32) + im2col(K=2, pad_lo=0) -> bf16 B1t[b][t][k=2ci+j] ----------------
__global__ __launch_bounds__(256) void gn1_im2col(const float* __restrict__ x,
    const float* __restrict__ w, const float* __restrict__ bv,
    __hip_bfloat16* __restrict__ B1t) {
  __shared__ float hs[16][262];
  int blk = blockIdx.x, bb = blk >> 5, g = blk & 31;
  size_t base = ((size_t)bb * Cc + g * 16) * Tt;
  const float* xp = x + base;
  float s = 0.f, ss = 0.f;
  for (int i = TID * 4; i < 16 * Tt; i += 1024) {
    float4 v = *reinterpret_cast<const float4*>(xp + i);
    s  += v.x + v.y + v.z + v.w;
    ss += v.x * v.x + v.y * v.y + v.z * v.z + v.w * v.w;
  }
  blockReduce2(s, ss);
  float mean = s * (1.f / 16384.f);
  float rstd = rsqrtf(ss * (1.f / 16384.f) - mean * mean + 1e-5f);

  char* ob = reinterpret_cast<char*>(B1t + (size_t)bb * Tt * 1024 + g * 32);
  for (int tc = 0; tc < 4; ++tc) {
    int tbase = tc * 256;
    __syncthreads();
    for (int task = TID; task < 1024; task += 256) {
      int row = task >> 6, c4 = task & 63;
      int ch = g * 16 + row;
      float sw = w[ch] * rstd;
      float sb = bv[ch] - mean * sw;
      float4 v = *reinterpret_cast<const float4*>(xp + (size_t)row * Tt + tbase + c4 * 4);
      hs[row][c4 * 4 + 0] = v.x * sw + sb;
      hs[row][c4 * 4 + 1] = v.y * sw + sb;
      hs[row][c4 * 4 + 2] = v.z * sw + sb;
      hs[row][c4 * 4 + 3] = v.w * sw + sb;
    }
    if (TID < 16) {
      int row = TID, t = tbase + 256;
      float val = 0.f;
      if (t < Tt) {
        int ch = g * 16 + row;
        float sw = w[ch] * rstd;
        float sb = bv[ch] - mean * sw;
        val = xp[(size_t)row * Tt + t] * sw + sb;
      }
      hs[row][256] = val;
    }
    __syncthreads();
    for (int task = TID; task < 1024; task += 256) {
      int t = task >> 2, cj = task & 3;
      int ci = cj * 4;
      uint4 u;
      u.x = pack2bf(hs[ci + 0][t], hs[ci + 0][t + 1]);
      u.y = pack2bf(hs[ci + 1][t], hs[ci + 1][t + 1]);
      u.z = pack2bf(hs[ci + 2][t], hs[ci + 2][t + 1]);
      u.w = pack2bf(hs[ci + 3][t], hs[ci + 3][t + 1]);
      *reinterpret_cast<uint4*>(ob + ((size_t)(tbase + t) * 1024 + cj * 8) * 2) = u;
    }
  }
}

// ---------------- im2col(K=4, pad_lo=1) on attn output -> bf16 B4t[b][t][k=4ci+j], coalesced ----------------
__global__ __launch_bounds__(256) void im2col_k4(const float* __restrict__ a,
    __hip_bfloat16* __restrict__ B4t) {
  __shared__ float hs[16][266];
  int bb = blockIdx.x >> 5, cg = blockIdx.x & 31;
  const float* ab = a + ((size_t)bb * Cc + cg * 16) * Tt;
  char* ob = reinterpret_cast<char*>(B4t + (size_t)bb * Tt * 2048 + cg * 64);
  for (int tc = 0; tc < 4; ++tc) {
    int tbase = tc * 256;
    __syncthreads();
    for (int task = TID; task < 1024; task += 256) {
      int row = task >> 6, c4 = task & 63;
      float4 v = *reinterpret_cast<const float4*>(ab + (size_t)row * Tt + tbase + c4 * 4);
      hs[row][c4 * 4 + 1] = v.x;
      hs[row][c4 * 4 + 2] = v.y;
      hs[row][c4 * 4 + 3] = v.z;
      hs[row][c4 * 4 + 4] = v.w;
    }
    if (TID < 48) {
      int row = TID / 3, e = TID % 3;
      int t = (e == 0) ? tbase - 1 : tbase + 256 + (e - 1);
      float v = (t >= 0 && t < Tt) ? ab[(size_t)row * Tt + t] : 0.f;
      int col = (e == 0) ? 0 : 257 + (e - 1);
      hs[row][col] = v;
    }
    __syncthreads();
    for (int task = TID; task < 2048; task += 256) {
      int t = task >> 3, cj = task & 7;
      int ci = cj * 2;
      uint4 u;
      u.x = pack2bf(hs[ci][t],     hs[ci][t + 1]);
      u.y = pack2bf(hs[ci][t + 2], hs[ci][t + 3]);
      u.z = pack2bf(hs[ci + 1][t],     hs[ci + 1][t + 1]);
      u.w = pack2bf(hs[ci + 1][t + 2], hs[ci + 1][t + 3]);
      *reinterpret_cast<uint4*>(ob + ((size_t)(tbase + t) * 2048 + cj * 8) * 2) = u;
    }
  }
}

// ---------------- f32 -> bf16 cast (weights) ----------------
__global__ __launch_bounds__(256) void cast_bf16(const float* __restrict__ in,
    __hip_bfloat16* __restrict__ out, int n) {
  int i = (blockIdx.x * 256 + TID) * 4;
  if (i >= n) return;
  float4 v = *reinterpret_cast<const float4*>(in + i);
  *reinterpret_cast<unsigned int*>(out + i)     = pack2bf(v.x, v.y);
  *reinterpret_cast<unsigned int*>(out + i + 2) = pack2bf(v.z, v.w);
}

// ---------------- bf16 MFMA GEMM v3: 4-deep prefetch ring, counted vmcnt (T4) ----------------
// C[b][o][t] = sum_k A[o][k] * Bt[b][t][k] + bias[o]. BK=32, 4 waves 2x2.
// One barrier per K-step; loads stay in flight across 3 steps (never vmcnt(0) mid-loop).
template<int K, int MT, int NT>
__global__ __launch_bounds__(256) void gemm_bt3(const __hip_bfloat16* __restrict__ A,
    const __hip_bfloat16* __restrict__ Bt, const float* __restrict__ bias,
    float* __restrict__ C, int M) {
  constexpr int MF = MT / 16, NFr = NT / 16;
  constexpr int CH = MF + NFr;
  constexpr int MW = MF / 2, NW = NFr / 2;
  constexpr int NKT = K / 32;
  constexpr int L = CH / 4;          // global_load_lds per thread per stage
  __shared__ __align__(16) char lds[4 * CH * 1024];
  int t0 = blockIdx.x * NT, o0 = blockIdx.y * MT, bz = blockIdx.z;
  int wave = TID >> 6, lane = TID & 63;
  int l4 = lane >> 4, r15 = lane & 15;
  int wm = wave >> 1, wn = wave & 1;
  const __hip_bfloat16* aBase = A + ((size_t)o0 + r15) * K + l4 * 8;
  const __hip_bfloat16* bBase = Bt + ((size_t)bz * 1024 + t0 + r15) * K + l4 * 8;

  f32x4 acc[MW][NW];
  f32x4 zz = {0.f, 0.f, 0.f, 0.f};
  #pragma unroll
  for (int m = 0; m < MW; ++m)
    #pragma unroll
    for (int n = 0; n < NW; ++n) acc[m][n] = zz;

  auto stage = [&](int kt) {
    char* dst = lds + (kt & 3) * (CH * 1024);
    #pragma unroll
    for (int c = 0; c < CH / 4; ++c) {
      int ch = c * 4 + wave;
      const __hip_bfloat16* src = (ch < MF)
          ? (aBase + (size_t)ch * 16 * K + kt * 32)
          : (bBase + (size_t)(ch - MF) * 16 * K + kt * 32);
      async16(src, dst + ch * 1024 + lane * 16);
    }
  };

  stage(0);
  stage(1);
  stage(2);
  wait_vmcnt<2 * L>();               // stage(0) landed
  __builtin_amdgcn_s_barrier();

  for (int kt = 0; kt < NKT; ++kt) {
    if (kt + 3 < NKT) stage(kt + 3);
    char* cur = lds + (kt & 3) * (CH * 1024);
    bf16x8 af[MW], bfr[NW];
    #pragma unroll
    for (int m = 0; m < MW; ++m)
      af[m] = *reinterpret_cast<const bf16x8*>(cur + (wm * MW + m) * 1024 + lane * 16);
    #pragma unroll
    for (int n = 0; n < NW; ++n)
      bfr[n] = *reinterpret_cast<const bf16x8*>(cur + (MF + wn * NW + n) * 1024 + lane * 16);
    #pragma unroll
    for (int m = 0; m < MW; ++m)
      #pragma unroll
      for (int n = 0; n < NW; ++n)
        acc[m][n] = __builtin_amdgcn_mfma_f32_16x16x32_bf16(af[m], bfr[n], acc[m][n], 0, 0, 0);
    if (kt + 1 < NKT) {
      int rem = NKT - 2 - kt;        // stages allowed to remain in flight (beyond kt+1)
      if (rem >= 2)      wait_vmcnt<2 * L>();
      else if (rem == 1) wait_vmcnt<L>();
      else               wait_vmcnt<0>();
      __builtin_amdgcn_s_barrier();
    }
  }

  #pragma unroll
  for (int m = 0; m < MW; ++m)
    #pragma unroll
    for (int n = 0; n < NW; ++n) {
      int ocol = t0 + (wn * NW + n) * 16 + r15;
      #pragma unroll
      for (int r = 0; r < 4; ++r) {
        int orow = o0 + (wm * MW + m) * 16 + l4 * 4 + r;
        C[((size_t)bz * M + orow) * 1024 + ocol] = acc[m][n][r] + bias[orow];
      }
    }
}

// ---------------- generic GroupNorm stats ----------------
__global__ __launch_bounds__(256) void gn_stats_kernel(const float* __restrict__ x,
    float2* __restrict__ stats, int n) {
  const float* p = x + (size_t)blockIdx.x * n;
  float s = 0.f, ss = 0.f;
  for (int i = TID * 4; i < n; i += 1024) {
    float4 v = *reinterpret_cast<const float4*>(p + i);
    s  += v.x + v.y + v.z + v.w;
    ss += v.x * v.x + v.y * v.y + v.z * v.z + v.w * v.w;
  }
  blockReduce2(s, ss);
  if (TID == 0) {
    float mean = s / (float)n;
    float var = ss / (float)n - mean * mean;
    stats[blockIdx.x] = make_float2(mean, rsqrtf(var + 1e-5f));
  }
}

// ---------------- fused GN(8)+Mish + build attn input images ----------------
__global__ __launch_bounds__(256) void gn2_prep(const float* __restrict__ qkv,
    const float2* __restrict__ st, const float* __restrict__ w, const float* __restrict__ bv,
    char* __restrict__ qTp, char* __restrict__ kimg, char* __restrict__ vimg) {
  __shared__ unsigned short hbf[192 * 66];
  int tl = blockIdx.x & 15, hb = blockIdx.x >> 4;
  int b = hb >> 3, hd = hb & 7;
  const float* base = qkv + ((size_t)b * C3 + hd * 192) * Tt + tl * 64;
  float2 ms = st[b * 8 + hd];
  for (int task = TID; task < 768; task += 256) {
    int row = task >> 2, seg = task & 3;
    int ch = hd * 192 + row;
    float sw = w[ch] * ms.y;
    float sb = bv[ch] - ms.x * sw;
    const float* src = base + (size_t)row * Tt + seg * 16;
    unsigned int* dst = reinterpret_cast<unsigned int*>(&hbf[row * 66 + seg * 16]);
    #pragma unroll
    for (int q4 = 0; q4 < 4; ++q4) {
      float4 v = *reinterpret_cast<const float4*>(src + q4 * 4);
      dst[q4 * 2]     = pack2bf(mishf(v.x * sw + sb), mishf(v.y * sw + sb));
      dst[q4 * 2 + 1] = pack2bf(mishf(v.z * sw + sb), mishf(v.w * sw + sb));
    }
  }
  __syncthreads();
  size_t tileof = ((size_t)hb * 16 + tl) * 8192;
  {
    int t = TID & 63, sel = TID >> 6;
    int img = sel >> 1, half = sel & 1;
    char* obase = (img == 0 ? qTp : kimg) + tileof + (size_t)t * 128;
    #pragma unroll
    for (int cc = 0; cc < 4; ++cc) {
      int chunk = half * 4 + cc;
      uint4 u;
      unsigned int* up = reinterpret_cast<unsigned int*>(&u);
      #pragma unroll
      for (int j = 0; j < 4; ++j) {
        int c = chunk * 8 + j * 2;
        unsigned int lo = hbf[(img * 64 + c) * 66 + t];
        unsigned int hi = hbf[(img * 64 + c + 1) * 66 + t];
        up[j] = lo | (hi << 16);
      }
      int cpos = (img == 0) ? chunk : (chunk ^ (t & 7));
      *reinterpret_cast<uint4*>(obase + cpos * 16) = u;
    }
  }
  {
    int c = TID & 63, qtr = TID >> 6;
    const unsigned int* vrow = reinterpret_cast<const unsigned int*>(&hbf[(128 + c) * 66]);
    char* obase = vimg + tileof + (size_t)c * 128;
    #pragma unroll
    for (int k = 0; k < 2; ++k) {
      int chunk = qtr * 2 + k;
      uint4 u;
      unsigned int* up = reinterpret_cast<unsigned int*>(&u);
      #pragma unroll
      for (int j = 0; j < 4; ++j) up[j] = vrow[chunk * 4 + j];
      *reinterpret_cast<uint4*>(obase + (chunk ^ (c & 7)) * 16) = u;
    }
  }
}

// ---------------- MFMA flash attention v2: async-staged images, double-buffered ----------------
__global__ __launch_bounds__(256) void attn_mfma2(const char* __restrict__ qTp,
    const char* __restrict__ kimg, const char* __restrict__ vimg,
    float* __restrict__ a) {
  __shared__ __align__(16) char smem[40960];
  char* kbuf0 = smem;
  char* kbuf1 = smem + 8192;
  char* vbuf0 = smem + 16384;
  char* vbuf1 = smem + 24576;
  char* pp    = smem + 32768;
  char* ov    = smem;

  int tl = blockIdx.x, hb = blockIdx.y;
  int b = hb >> 3, hd = hb & 7;
  int lane = TID & 63, wave = TID >> 6;
  int l4 = lane >> 4, r15 = lane & 15;
  size_t ibase = (size_t)hb * 16 * 8192;
  const char* ksrc = kimg + ibase;
  const char* vsrc = vimg + ibase;

  #pragma unroll
  for (int j = 0; j < 2; ++j) {
    int u = j * 256 + TID;
    async16(ksrc + u * 16, kbuf0 + u * 16);
    async16(vsrc + u * 16, vbuf0 + u * 16);
  }
  bf16x8 aq[2];
  int tg = wave * 16 + r15;
  const char* qrow = qTp + ibase + (size_t)tl * 8192 + (size_t)tg * 128;
  aq[0] = *reinterpret_cast<const bf16x8*>(qrow + l4 * 16);
  aq[1] = *reinterpret_cast<const bf16x8*>(qrow + 64 + l4 * 16);

  f32x4 osum[4];
  f32x4 zz = {0.f, 0.f, 0.f, 0.f};
  #pragma unroll
  for (int cf = 0; cf < 4; ++cf) osum[cf] = zz;
  float mrow[4] = {-1e30f, -1e30f, -1e30f, -1e30f};
  float lrow[4] = {0.f, 0.f, 0.f, 0.f};
  __syncthreads();

  for (int it = 0; it < 16; ++it) {
    char* kcur = (it & 1) ? kbuf1 : kbuf0;
    char* vcur = (it & 1) ? vbuf1 : vbuf0;
    if (it < 15) {
      char* knxt = (it & 1) ? kbuf0 : kbuf1;
      char* vnxt = (it & 1) ? vbuf0 : vbuf1;
      const char* kn = ksrc + (size_t)(it + 1) * 8192;
      const char* vn = vsrc + (size_t)(it + 1) * 8192;
      #pragma unroll
      for (int j = 0; j < 2; ++j) {
        int u = j * 256 + TID;
        async16(kn + u * 16, knxt + u * 16);
        async16(vn + u * 16, vnxt + u * 16);
      }
    }
    f32x4 sc[4];
    #pragma unroll
    for (int sf = 0; sf < 4; ++sf) sc[sf] = zz;
    #pragma unroll
    for (int sf = 0; sf < 4; ++sf) {
      int sr = sf * 16 + r15;
      #pragma unroll
      for (int kk = 0; kk < 2; ++kk) {
        bf16x8 bk = *reinterpret_cast<const bf16x8*>(kcur + sr * 128 + (((kk * 4 + l4) ^ (sr & 7)) << 4));
        sc[sf] = __builtin_amdgcn_mfma_f32_16x16x32_bf16(aq[kk], bk, sc[sf], 0, 0, 0);
      }
    }
    float tmax[4];
    #pragma unroll
    for (int r = 0; r < 4; ++r)
      tmax[r] = fmaxf(fmaxf(sc[0][r], sc[1][r]), fmaxf(sc[2][r], sc[3][r]));
    #pragma unroll
    for (int off = 1; off < 16; off <<= 1)
      #pragma unroll
      for (int r = 0; r < 4; ++r) tmax[r] = fmaxf(tmax[r], __shfl_xor(tmax[r], off));
    float alpha[4];
    #pragma unroll
    for (int r = 0; r < 4; ++r) {
      float mnew = fmaxf(mrow[r], tmax[r]);
      alpha[r] = __expf((mrow[r] - mnew) * 0.125f);
      mrow[r] = mnew;
      lrow[r] *= alpha[r];
    }
    #pragma unroll
    for (int cf = 0; cf < 4; ++cf)
      #pragma unroll
      for (int r = 0; r < 4; ++r) osum[cf][r] *= alpha[r];
    char* pw = pp + wave * 2048;
    float psum[4] = {0.f, 0.f, 0.f, 0.f};
    #pragma unroll
    for (int sf = 0; sf < 4; ++sf) {
      int s = sf * 16 + r15;
      #pragma unroll
      for (int r = 0; r < 4; ++r) {
        float p = __expf((sc[sf][r] - mrow[r]) * 0.125f);
        psum[r] += p;
        int tlc = l4 * 4 + r;
        *reinterpret_cast<__hip_bfloat16*>(pw + tlc * 128 + ((((s >> 3) ^ (tlc & 7)) << 4) | ((s & 7) * 2)))
            = __float2bfloat16(p);
      }
    }
    #pragma unroll
    for (int r = 0; r < 4; ++r) lrow[r] += psum[r];
    asm volatile("s_waitcnt lgkmcnt(0)" ::: "memory");
    __builtin_amdgcn_sched_barrier(0);

    bf16x8 pa[2];
    #pragma unroll
    for (int kk = 0; kk < 2; ++kk)
      pa[kk] = *reinterpret_cast<const bf16x8*>(pw + r15 * 128 + (((kk * 4 + l4) ^ (r15 & 7)) << 4));
    #pragma unroll
    for (int cf = 0; cf < 4; ++cf) {
      int cr = cf * 16 + r15;
      #pragma unroll
      for (int kk = 0; kk < 2; ++kk) {
        bf16x8 bv = *reinterpret_cast<const bf16x8*>(vcur + cr * 128 + (((kk * 4 + l4) ^ (cr & 7)) << 4));
        osum[cf] = __builtin_amdgcn_mfma_f32_16x16x32_bf16(pa[kk], bv, osum[cf], 0, 0, 0);
      }
    }
    __syncthreads();
  }

  #pragma unroll
  for (int off = 1; off < 16; off <<= 1)
    #pragma unroll
    for (int r = 0; r < 4; ++r) lrow[r] += __shfl_xor(lrow[r], off);
  float linv[4];
  #pragma unroll
  for (int r = 0; r < 4; ++r) linv[r] = 1.f / lrow[r];

  #pragma unroll
  for (int cf = 0; cf < 4; ++cf) {
    int c = cf * 16 + r15;
    #pragma unroll
    for (int r = 0; r < 4; ++r) {
      int t = wave * 16 + l4 * 4 + r;
      *reinterpret_cast<float*>(ov + c * 256 + ((((t >> 2) ^ (c & 7)) << 4) | ((t & 3) * 4)))
          = osum[cf][r] * linv[r];
    }
  }
  __syncthreads();
  float* ap = a + ((size_t)b * Cc + hd * 64) * Tt + tl * 64;
  for (int u = TID; u < 1024; u += 256) {
    int c = u >> 4, tq = u & 15;
    float4 o4 = *reinterpret_cast<const float4*>(ov + c * 256 + ((tq ^ (c & 7)) << 4));
    *reinterpret_cast<float4*>(ap + (size_t)c * Tt + tq * 4) = o4;
  }
}

// ---------------- final: out = x + mish(gn(y2)) in-place on d_out ----------------
__global__ __launch_bounds__(256) void final_kernel(const float* __restrict__ x,
    float* __restrict__ y, const float2* __restrict__ st,
    const float* __restrict__ w, const float* __restrict__ bv) {
  size_t i = ((size_t)blockIdx.x * 256 + TID) * 4;
  int ch = (int)((i >> 10) & (Cc - 1));
  int b = (int)(i >> 19);
  float2 ms = st[b * 8 + (ch >> 6)];
  float sw = w[ch] * ms.y;
  float sb = bv[ch] - ms.x * sw;
  float4 v  = *reinterpret_cast<const float4*>(y + i);
  float4 xv = *reinterpret_cast<const float4*>(x + i);
  v.x = xv.x + mishf(v.x * sw + sb);
  v.y = xv.y + mishf(v.y * sw + sb);
  v.z = xv.z + mishf(v.z * sw + sb);
  v.w = xv.w + mishf(v.w * sw + sb);
  *reinterpret_cast<float4*>(y + i) = v;
}

extern "C" void kernel_launch(void* const* d_in, const int* in_sizes, int n_in,
                              void* d_out, int out_size, void* d_ws, size_t ws_size,
                              hipStream_t stream) {
  const float* x     = (const float*)d_in[0];
  const float* gn_w  = (const float*)d_in[1];
  const float* gn_b  = (const float*)d_in[2];
  const float* wqkv  = (const float*)d_in[3];
  const float* bqkv  = (const float*)d_in[4];
  const float* gnq_w = (const float*)d_in[5];
  const float* gnq_b = (const float*)d_in[6];
  const float* wproj = (const float*)d_in[7];
  const float* bproj = (const float*)d_in[8];
  const float* gnp_w = (const float*)d_in[9];
  const float* gnp_b = (const float*)d_in[10];
  float* out = (float*)d_out;

  char* ws = (char*)d_ws;
  const size_t MB = 1024 * 1024;
  float* qkv = (float*)ws;                               // [0,48MB)   step3 -> step5
  float* hbuf = (float*)ws;                              // [0,16MB)   step6 -> step7 (qkv dead)
  __hip_bfloat16* B4t = (__hip_bfloat16*)(ws + 16 * MB); // [16,48MB)  step7 -> step9
  __hip_bfloat16* A1  = (__hip_bfloat16*)(ws + 48 * MB); // [48,51MB)  step1 -> step3
  char* vimg = ws + 48 * MB;                             // [48,56MB)  step5 -> step6 (A1 dead)
  __hip_bfloat16* A2  = (__hip_bfloat16*)(ws + 48 * MB); // [48,50MB)  step8 -> step9 (vimg dead)
  float2* st2 = (float2*)(ws + 63 * MB);
  float2* st3 = st2 + 64;
  __hip_bfloat16* B1t = (__hip_bfloat16*)d_out;          // d_out as B1t  step2 -> step3
  char* qTp  = (char*)d_out;                             // d_out[0,8MB)  step5 -> step6
  char* kimg = (char*)d_out + 8 * MB;                    // d_out[8,16MB) step5 -> step6

  dim3 blk(256);
  cast_bf16<<<1536, blk, 0, stream>>>(wqkv, A1, C3 * 1024);                        // 1
  gn1_im2col<<<256, blk, 0, stream>>>(x, gn_w, gn_b, B1t);                         // 2
  gemm_bt3<1024, 64, 128><<<dim3(8, 24, 8), blk, 0, stream>>>(A1, B1t, bqkv, qkv, C3); // 3
  gn_stats_kernel<<<64, blk, 0, stream>>>(qkv, st2, 192 * 1024);                   // 4
  gn2_prep<<<1024, blk, 0, stream>>>(qkv, st2, gnq_w, gnq_b, qTp, kimg, vimg);     // 5
  attn_mfma2<<<dim3(16, 64), blk, 0, stream>>>(qTp, kimg, vimg, hbuf);             // 6
  im2col_k4<<<256, blk, 0, stream>>>(hbuf, B4t);                                   // 7
  cast_bf16<<<1024, blk, 0, stream>>>(wproj, A2, Cc * 2048);                       // 8
  gemm_bt3<2048, 64, 64><<<dim3(16, 8, 8), blk, 0, stream>>>(A2, B4t, bproj, out, Cc); // 9
  gn_stats_kernel<<<64, blk, 0, stream>>>(out, st3, 64 * 1024);                    // 10
  final_kernel<<<4096, blk, 0, stream>>>(x, out, st3, gnp_w, gnp_b);               // 11
}

// Round 7
// 343.244 us; speedup vs baseline: 1.0700x; 1.0652x over previous
//
#include <hip/hip_runtime.h>
#include <hip/hip_bf16.h>
#include <math.h>

#define TID threadIdx.x

constexpr int Cc = 512, Tt = 1024, C3 = 1536;

typedef __attribute__((ext_vector_type(8))) __bf16 bf16x8;
typedef __attribute__((ext_vector_type(4))) float f32x4;

__device__ __forceinline__ void async16(const void* g, void* l) {
  __builtin_amdgcn_global_load_lds(
      (const __attribute__((address_space(1))) unsigned int*)g,
      (__attribute__((address_space(3))) unsigned int*)l, 16, 0, 0);
}

template<int N> __device__ __forceinline__ void wait_vmcnt() {
  asm volatile("s_waitcnt vmcnt(%0)" :: "n"(N) : "memory");
}

__device__ __forceinline__ unsigned int pack2bf(float a, float b) {
  __hip_bfloat162 h;
  h.x = __float2bfloat16(a);
  h.y = __float2bfloat16(b);
  return *reinterpret_cast<unsigned int*>(&h);
}

__device__ __forceinline__ float bf2f(unsigned short u) {
  unsigned int t = ((unsigned int)u) << 16;
  union { unsigned int i; float f; } c;
  c.i = t;
  return c.f;
}

__device__ __forceinline__ float mishf(float x) {
  float sp = (x > 20.f) ? x : log1pf(__expf(x));
  return x * tanhf(sp);
}

__device__ __forceinline__ void blockReduce2(float& s, float& ss) {
  #pragma unroll
  for (int off = 32; off > 0; off >>= 1) {
    s  += __shfl_xor(s,  off);
    ss += __shfl_xor(ss, off);
  }
  __shared__ float ls[4], lss[4];
  int w = TID >> 6;
  if ((TID & 63) == 0) { ls[w] = s; lss[w] = ss; }
  __syncthreads();
  s  = ls[0] + ls[1] + ls[2] + ls[3];
  ss = lss[0] + lss[1] + lss[2] + lss[3];
}

// ---------------- zero the raw-stat accumulators (256 floats) ----------------
__global__ void zero_stats(float* p) { p[TID] = 0.f; }

// ---------------- fused GN(32) + im2col(K=2, pad_lo=0) -> bf16 B1t[b][t][k=2ci+j] ----------------
__global__ __launch_bounds__(256) void gn1_im2col(const float* __restrict__ x,
    const float* __restrict__ w, const float* __restrict__ bv,
    __hip_bfloat16* __restrict__ B1t) {
  __shared__ float hs[16][262];
  int blk = blockIdx.x, bb = blk >> 5, g = blk & 31;
  size_t base = ((size_t)bb * Cc + g * 16) * Tt;
  const float* xp = x + base;
  float s = 0.f, ss = 0.f;
  for (int i = TID * 4; i < 16 * Tt; i += 1024) {
    float4 v = *reinterpret_cast<const float4*>(xp + i);
    s  += v.x + v.y + v.z + v.w;
    ss += v.x * v.x + v.y * v.y + v.z * v.z + v.w * v.w;
  }
  blockReduce2(s, ss);
  float mean = s * (1.f / 16384.f);
  float rstd = rsqrtf(ss * (1.f / 16384.f) - mean * mean + 1e-5f);

  char* ob = reinterpret_cast<char*>(B1t + (size_t)bb * Tt * 1024 + g * 32);
  for (int tc = 0; tc < 4; ++tc) {
    int tbase = tc * 256;
    __syncthreads();
    for (int task = TID; task < 1024; task += 256) {
      int row = task >> 6, c4 = task & 63;
      int ch = g * 16 + row;
      float sw = w[ch] * rstd;
      float sb = bv[ch] - mean * sw;
      float4 v = *reinterpret_cast<const float4*>(xp + (size_t)row * Tt + tbase + c4 * 4);
      hs[row][c4 * 4 + 0] = v.x * sw + sb;
      hs[row][c4 * 4 + 1] = v.y * sw + sb;
      hs[row][c4 * 4 + 2] = v.z * sw + sb;
      hs[row][c4 * 4 + 3] = v.w * sw + sb;
    }
    if (TID < 16) {
      int row = TID, t = tbase + 256;
      float val = 0.f;
      if (t < Tt) {
        int ch = g * 16 + row;
        float sw = w[ch] * rstd;
        float sb = bv[ch] - mean * sw;
        val = xp[(size_t)row * Tt + t] * sw + sb;
      }
      hs[row][256] = val;
    }
    __syncthreads();
    for (int task = TID; task < 1024; task += 256) {
      int t = task >> 2, cj = task & 3;
      int ci = cj * 4;
      uint4 u;
      u.x = pack2bf(hs[ci + 0][t], hs[ci + 0][t + 1]);
      u.y = pack2bf(hs[ci + 1][t], hs[ci + 1][t + 1]);
      u.z = pack2bf(hs[ci + 2][t], hs[ci + 2][t + 1]);
      u.w = pack2bf(hs[ci + 3][t], hs[ci + 3][t + 1]);
      *reinterpret_cast<uint4*>(ob + ((size_t)(tbase + t) * 1024 + cj * 8) * 2) = u;
    }
  }
}

// ---------------- im2col(K=4, pad_lo=1) on attn output -> bf16 B4t[b][t][k=4ci+j], coalesced ----------------
__global__ __launch_bounds__(256) void im2col_k4(const float* __restrict__ a,
    __hip_bfloat16* __restrict__ B4t) {
  __shared__ float hs[16][266];
  int bb = blockIdx.x >> 5, cg = blockIdx.x & 31;
  const float* ab = a + ((size_t)bb * Cc + cg * 16) * Tt;
  char* ob = reinterpret_cast<char*>(B4t + (size_t)bb * Tt * 2048 + cg * 64);
  for (int tc = 0; tc < 4; ++tc) {
    int tbase = tc * 256;
    __syncthreads();
    for (int task = TID; task < 1024; task += 256) {
      int row = task >> 6, c4 = task & 63;
      float4 v = *reinterpret_cast<const float4*>(ab + (size_t)row * Tt + tbase + c4 * 4);
      hs[row][c4 * 4 + 1] = v.x;
      hs[row][c4 * 4 + 2] = v.y;
      hs[row][c4 * 4 + 3] = v.z;
      hs[row][c4 * 4 + 4] = v.w;
    }
    if (TID < 48) {
      int row = TID / 3, e = TID % 3;
      int t = (e == 0) ? tbase - 1 : tbase + 256 + (e - 1);
      float v = (t >= 0 && t < Tt) ? ab[(size_t)row * Tt + t] : 0.f;
      int col = (e == 0) ? 0 : 257 + (e - 1);
      hs[row][col] = v;
    }
    __syncthreads();
    for (int task = TID; task < 2048; task += 256) {
      int t = task >> 3, cj = task & 7;
      int ci = cj * 2;
      uint4 u;
      u.x = pack2bf(hs[ci][t],     hs[ci][t + 1]);
      u.y = pack2bf(hs[ci][t + 2], hs[ci][t + 3]);
      u.z = pack2bf(hs[ci + 1][t],     hs[ci + 1][t + 1]);
      u.w = pack2bf(hs[ci + 1][t + 2], hs[ci + 1][t + 3]);
      *reinterpret_cast<uint4*>(ob + ((size_t)(tbase + t) * 2048 + cj * 8) * 2) = u;
    }
  }
}

// ---------------- f32 -> bf16 cast (weights) ----------------
__global__ __launch_bounds__(256) void cast_bf16(const float* __restrict__ in,
    __hip_bfloat16* __restrict__ out, int n) {
  int i = (blockIdx.x * 256 + TID) * 4;
  if (i >= n) return;
  float4 v = *reinterpret_cast<const float4*>(in + i);
  *reinterpret_cast<unsigned int*>(out + i)     = pack2bf(v.x, v.y);
  *reinterpret_cast<unsigned int*>(out + i + 2) = pack2bf(v.z, v.w);
}

// ---------------- bf16 MFMA GEMM v4: 128x128 tile, XCD-chunked swizzle, 4-deep vmcnt ring,
//                  fused GroupNorm raw-stat accumulation + optional bf16 output ----------------
// C[b][o][t] = sum_k A[o][k] * Bt[b][t][k] + bias[o];  statraw[2g] += sum, statraw[2g+1] += sum^2
template<int K, int NM, int NTt, int GROWS, int NGRP, bool BF16OUT>
__global__ __launch_bounds__(256) void gemm_bt4(const __hip_bfloat16* __restrict__ A,
    const __hip_bfloat16* __restrict__ Bt, const float* __restrict__ bias,
    void* __restrict__ Cout, float* __restrict__ statraw) {
  constexpr int MT = 128, NT = 128;
  constexpr int MF = MT / 16, NFr = NT / 16;   // 8, 8
  constexpr int CH = MF + NFr;                 // 16 chunks of 1KB per stage
  constexpr int MW = MF / 2, NW = NFr / 2;     // 4, 4
  constexpr int NKT = K / 32;
  constexpr int L = CH / 4;                    // loads per thread per stage (4)
  constexpr int M = NM * MT;
  __shared__ __align__(16) char lds[4 * CH * 1024];

  // XCD-chunked bijective swizzle (grid divisible by 8): consecutive lin share the B panel.
  int q = (8 * NTt * NM) >> 3;
  int lin = (blockIdx.x & 7) * q + (blockIdx.x >> 3);
  int o0i = lin % NM;
  int t0i = (lin / NM) % NTt;
  int bz  = lin / (NM * NTt);
  int t0 = t0i * NT, o0 = o0i * MT;

  int wave = TID >> 6, lane = TID & 63;
  int l4 = lane >> 4, r15 = lane & 15;
  int wm = wave >> 1, wn = wave & 1;
  const __hip_bfloat16* aBase = A + ((size_t)o0 + r15) * K + l4 * 8;
  const __hip_bfloat16* bBase = Bt + ((size_t)bz * 1024 + t0 + r15) * K + l4 * 8;

  f32x4 acc[MW][NW];
  f32x4 zz = {0.f, 0.f, 0.f, 0.f};
  #pragma unroll
  for (int m = 0; m < MW; ++m)
    #pragma unroll
    for (int n = 0; n < NW; ++n) acc[m][n] = zz;

  auto stage = [&](int kt) {
    char* dst = lds + (kt & 3) * (CH * 1024);
    #pragma unroll
    for (int c = 0; c < CH / 4; ++c) {
      int ch = c * 4 + wave;
      const __hip_bfloat16* src = (ch < MF)
          ? (aBase + (size_t)ch * 16 * K + kt * 32)
          : (bBase + (size_t)(ch - MF) * 16 * K + kt * 32);
      async16(src, dst + ch * 1024 + lane * 16);
    }
  };

  stage(0);
  stage(1);
  stage(2);
  wait_vmcnt<2 * L>();
  __builtin_amdgcn_s_barrier();

  for (int kt = 0; kt < NKT; ++kt) {
    if (kt + 3 < NKT) stage(kt + 3);
    char* cur = lds + (kt & 3) * (CH * 1024);
    bf16x8 af[MW], bfr[NW];
    #pragma unroll
    for (int m = 0; m < MW; ++m)
      af[m] = *reinterpret_cast<const bf16x8*>(cur + (wm * MW + m) * 1024 + lane * 16);
    #pragma unroll
    for (int n = 0; n < NW; ++n)
      bfr[n] = *reinterpret_cast<const bf16x8*>(cur + (MF + wn * NW + n) * 1024 + lane * 16);
    #pragma unroll
    for (int m = 0; m < MW; ++m)
      #pragma unroll
      for (int n = 0; n < NW; ++n)
        acc[m][n] = __builtin_amdgcn_mfma_f32_16x16x32_bf16(af[m], bfr[n], acc[m][n], 0, 0, 0);
    if (kt + 1 < NKT) {
      int rem = NKT - 2 - kt;
      if (rem >= 2)      wait_vmcnt<2 * L>();
      else if (rem == 1) wait_vmcnt<L>();
      else               wait_vmcnt<0>();
      __builtin_amdgcn_s_barrier();
    }
  }

  // epilogue: store (+bias) and accumulate per-group raw stats
  #pragma unroll
  for (int m = 0; m < MW; ++m) {
    float s = 0.f, ss2 = 0.f;
    #pragma unroll
    for (int n = 0; n < NW; ++n) {
      int ocol = t0 + (wn * NW + n) * 16 + r15;
      #pragma unroll
      for (int r = 0; r < 4; ++r) {
        int orow = o0 + (wm * MW + m) * 16 + l4 * 4 + r;
        float v = acc[m][n][r] + bias[orow];
        if constexpr (BF16OUT)
          ((__hip_bfloat16*)Cout)[((size_t)bz * M + orow) * 1024 + ocol] = __float2bfloat16(v);
        else
          ((float*)Cout)[((size_t)bz * M + orow) * 1024 + ocol] = v;
        s += v;
        ss2 += v * v;
      }
    }
    #pragma unroll
    for (int off = 1; off < 64; off <<= 1) {
      s   += __shfl_xor(s, off);
      ss2 += __shfl_xor(ss2, off);
    }
    if (lane == 0) {
      int g = bz * NGRP + (o0 + (wm * MW + m) * 16) / GROWS;
      atomicAdd(&statraw[2 * g],     s);
      atomicAdd(&statraw[2 * g + 1], ss2);
    }
  }
}

// ---------------- fused GN(8)+Mish + build attn input images (bf16 qkv input, raw stats) ----------------
__global__ __launch_bounds__(256) void gn2_prep(const __hip_bfloat16* __restrict__ qkv,
    const float* __restrict__ straw, const float* __restrict__ w, const float* __restrict__ bv,
    char* __restrict__ qTp, char* __restrict__ kimg, char* __restrict__ vimg) {
  __shared__ unsigned short hbf[192 * 66];
  int tl = blockIdx.x & 15, hb = blockIdx.x >> 4;
  int b = hb >> 3, hd = hb & 7;
  float rs = straw[2 * (b * 8 + hd)], rq = straw[2 * (b * 8 + hd) + 1];
  float mean = rs * (1.f / 196608.f);
  float rstd = rsqrtf(fmaxf(rq * (1.f / 196608.f) - mean * mean, 0.f) + 1e-5f);
  for (int task = TID; task < 768; task += 256) {
    int row = task >> 2, seg = task & 3;
    int ch = hd * 192 + row;
    float sw = w[ch] * rstd;
    float sb = bv[ch] - mean * sw;
    const uint4* src = reinterpret_cast<const uint4*>(
        qkv + ((size_t)(b * C3 + ch)) * 1024 + tl * 64 + seg * 16);
    uint4 u0 = src[0], u1 = src[1];
    unsigned int uu[8] = {u0.x, u0.y, u0.z, u0.w, u1.x, u1.y, u1.z, u1.w};
    unsigned int* dst = reinterpret_cast<unsigned int*>(&hbf[row * 66 + seg * 16]);
    #pragma unroll
    for (int j = 0; j < 8; ++j) {
      float a = mishf(bf2f((unsigned short)(uu[j] & 0xffff)) * sw + sb);
      float c = mishf(bf2f((unsigned short)(uu[j] >> 16)) * sw + sb);
      dst[j] = pack2bf(a, c);
    }
  }
  __syncthreads();
  size_t tileof = ((size_t)hb * 16 + tl) * 8192;
  {
    int t = TID & 63, sel = TID >> 6;
    int img = sel >> 1, half = sel & 1;
    char* obase = (img == 0 ? qTp : kimg) + tileof + (size_t)t * 128;
    #pragma unroll
    for (int cc = 0; cc < 4; ++cc) {
      int chunk = half * 4 + cc;
      uint4 u;
      unsigned int* up = reinterpret_cast<unsigned int*>(&u);
      #pragma unroll
      for (int j = 0; j < 4; ++j) {
        int c = chunk * 8 + j * 2;
        unsigned int lo = hbf[(img * 64 + c) * 66 + t];
        unsigned int hi = hbf[(img * 64 + c + 1) * 66 + t];
        up[j] = lo | (hi << 16);
      }
      int cpos = (img == 0) ? chunk : (chunk ^ (t & 7));
      *reinterpret_cast<uint4*>(obase + cpos * 16) = u;
    }
  }
  {
    int c = TID & 63, qtr = TID >> 6;
    const unsigned int* vrow = reinterpret_cast<const unsigned int*>(&hbf[(128 + c) * 66]);
    char* obase = vimg + tileof + (size_t)c * 128;
    #pragma unroll
    for (int k = 0; k < 2; ++k) {
      int chunk = qtr * 2 + k;
      uint4 u;
      unsigned int* up = reinterpret_cast<unsigned int*>(&u);
      #pragma unroll
      for (int j = 0; j < 4; ++j) up[j] = vrow[chunk * 4 + j];
      *reinterpret_cast<uint4*>(obase + (chunk ^ (c & 7)) * 16) = u;
    }
  }
}

// ---------------- MFMA flash attention v2: async-staged images, double-buffered ----------------
__global__ __launch_bounds__(256) void attn_mfma2(const char* __restrict__ qTp,
    const char* __restrict__ kimg, const char* __restrict__ vimg,
    float* __restrict__ a) {
  __shared__ __align__(16) char smem[40960];
  char* kbuf0 = smem;
  char* kbuf1 = smem + 8192;
  char* vbuf0 = smem + 16384;
  char* vbuf1 = smem + 24576;
  char* pp    = smem + 32768;
  char* ov    = smem;

  int tl = blockIdx.x, hb = blockIdx.y;
  int b = hb >> 3, hd = hb & 7;
  int lane = TID & 63, wave = TID >> 6;
  int l4 = lane >> 4, r15 = lane & 15;
  size_t ibase = (size_t)hb * 16 * 8192;
  const char* ksrc = kimg + ibase;
  const char* vsrc = vimg + ibase;

  #pragma unroll
  for (int j = 0; j < 2; ++j) {
    int u = j * 256 + TID;
    async16(ksrc + u * 16, kbuf0 + u * 16);
    async16(vsrc + u * 16, vbuf0 + u * 16);
  }
  bf16x8 aq[2];
  int tg = wave * 16 + r15;
  const char* qrow = qTp + ibase + (size_t)tl * 8192 + (size_t)tg * 128;
  aq[0] = *reinterpret_cast<const bf16x8*>(qrow + l4 * 16);
  aq[1] = *reinterpret_cast<const bf16x8*>(qrow + 64 + l4 * 16);

  f32x4 osum[4];
  f32x4 zz = {0.f, 0.f, 0.f, 0.f};
  #pragma unroll
  for (int cf = 0; cf < 4; ++cf) osum[cf] = zz;
  float mrow[4] = {-1e30f, -1e30f, -1e30f, -1e30f};
  float lrow[4] = {0.f, 0.f, 0.f, 0.f};
  __syncthreads();

  for (int it = 0; it < 16; ++it) {
    char* kcur = (it & 1) ? kbuf1 : kbuf0;
    char* vcur = (it & 1) ? vbuf1 : vbuf0;
    if (it < 15) {
      char* knxt = (it & 1) ? kbuf0 : kbuf1;
      char* vnxt = (it & 1) ? vbuf0 : vbuf1;
      const char* kn = ksrc + (size_t)(it + 1) * 8192;
      const char* vn = vsrc + (size_t)(it + 1) * 8192;
      #pragma unroll
      for (int j = 0; j < 2; ++j) {
        int u = j * 256 + TID;
        async16(kn + u * 16, knxt + u * 16);
        async16(vn + u * 16, vnxt + u * 16);
      }
    }
    f32x4 sc[4];
    #pragma unroll
    for (int sf = 0; sf < 4; ++sf) sc[sf] = zz;
    #pragma unroll
    for (int sf = 0; sf < 4; ++sf) {
      int sr = sf * 16 + r15;
      #pragma unroll
      for (int kk = 0; kk < 2; ++kk) {
        bf16x8 bk = *reinterpret_cast<const bf16x8*>(kcur + sr * 128 + (((kk * 4 + l4) ^ (sr & 7)) << 4));
        sc[sf] = __builtin_amdgcn_mfma_f32_16x16x32_bf16(aq[kk], bk, sc[sf], 0, 0, 0);
      }
    }
    float tmax[4];
    #pragma unroll
    for (int r = 0; r < 4; ++r)
      tmax[r] = fmaxf(fmaxf(sc[0][r], sc[1][r]), fmaxf(sc[2][r], sc[3][r]));
    #pragma unroll
    for (int off = 1; off < 16; off <<= 1)
      #pragma unroll
      for (int r = 0; r < 4; ++r) tmax[r] = fmaxf(tmax[r], __shfl_xor(tmax[r], off));
    float alpha[4];
    #pragma unroll
    for (int r = 0; r < 4; ++r) {
      float mnew = fmaxf(mrow[r], tmax[r]);
      alpha[r] = __expf((mrow[r] - mnew) * 0.125f);
      mrow[r] = mnew;
      lrow[r] *= alpha[r];
    }
    #pragma unroll
    for (int cf = 0; cf < 4; ++cf)
      #pragma unroll
      for (int r = 0; r < 4; ++r) osum[cf][r] *= alpha[r];
    char* pw = pp + wave * 2048;
    float psum[4] = {0.f, 0.f, 0.f, 0.f};
    #pragma unroll
    for (int sf = 0; sf < 4; ++sf) {
      int s = sf * 16 + r15;
      #pragma unroll
      for (int r = 0; r < 4; ++r) {
        float p = __expf((sc[sf][r] - mrow[r]) * 0.125f);
        psum[r] += p;
        int tlc = l4 * 4 + r;
        *reinterpret_cast<__hip_bfloat16*>(pw + tlc * 128 + ((((s >> 3) ^ (tlc & 7)) << 4) | ((s & 7) * 2)))
            = __float2bfloat16(p);
      }
    }
    #pragma unroll
    for (int r = 0; r < 4; ++r) lrow[r] += psum[r];
    asm volatile("s_waitcnt lgkmcnt(0)" ::: "memory");
    __builtin_amdgcn_sched_barrier(0);

    bf16x8 pa[2];
    #pragma unroll
    for (int kk = 0; kk < 2; ++kk)
      pa[kk] = *reinterpret_cast<const bf16x8*>(pw + r15 * 128 + (((kk * 4 + l4) ^ (r15 & 7)) << 4));
    #pragma unroll
    for (int cf = 0; cf < 4; ++cf) {
      int cr = cf * 16 + r15;
      #pragma unroll
      for (int kk = 0; kk < 2; ++kk) {
        bf16x8 bv = *reinterpret_cast<const bf16x8*>(vcur + cr * 128 + (((kk * 4 + l4) ^ (cr & 7)) << 4));
        osum[cf] = __builtin_amdgcn_mfma_f32_16x16x32_bf16(pa[kk], bv, osum[cf], 0, 0, 0);
      }
    }
    __syncthreads();
  }

  #pragma unroll
  for (int off = 1; off < 16; off <<= 1)
    #pragma unroll
    for (int r = 0; r < 4; ++r) lrow[r] += __shfl_xor(lrow[r], off);
  float linv[4];
  #pragma unroll
  for (int r = 0; r < 4; ++r) linv[r] = 1.f / lrow[r];

  #pragma unroll
  for (int cf = 0; cf < 4; ++cf) {
    int c = cf * 16 + r15;
    #pragma unroll
    for (int r = 0; r < 4; ++r) {
      int t = wave * 16 + l4 * 4 + r;
      *reinterpret_cast<float*>(ov + c * 256 + ((((t >> 2) ^ (c & 7)) << 4) | ((t & 3) * 4)))
          = osum[cf][r] * linv[r];
    }
  }
  __syncthreads();
  float* ap = a + ((size_t)b * Cc + hd * 64) * Tt + tl * 64;
  for (int u = TID; u < 1024; u += 256) {
    int c = u >> 4, tq = u & 15;
    float4 o4 = *reinterpret_cast<const float4*>(ov + c * 256 + ((tq ^ (c & 7)) << 4));
    *reinterpret_cast<float4*>(ap + (size_t)c * Tt + tq * 4) = o4;
  }
}

// ---------------- final: out = x + mish(gn(y2)) in-place on d_out (raw stats) ----------------
__global__ __launch_bounds__(256) void final_kernel(const float* __restrict__ x,
    float* __restrict__ y, const float* __restrict__ straw,
    const float* __restrict__ w, const float* __restrict__ bv) {
  size_t i = ((size_t)blockIdx.x * 256 + TID) * 4;
  int ch = (int)((i >> 10) & (Cc - 1));
  int b = (int)(i >> 19);
  int g = b * 8 + (ch >> 6);
  float rs = straw[2 * g], rq = straw[2 * g + 1];
  float mean = rs * (1.f / 65536.f);
  float rstd = rsqrtf(fmaxf(rq * (1.f / 65536.f) - mean * mean, 0.f) + 1e-5f);
  float sw = w[ch] * rstd;
  float sb = bv[ch] - mean * sw;
  float4 v  = *reinterpret_cast<const float4*>(y + i);
  float4 xv = *reinterpret_cast<const float4*>(x + i);
  v.x = xv.x + mishf(v.x * sw + sb);
  v.y = xv.y + mishf(v.y * sw + sb);
  v.z = xv.z + mishf(v.z * sw + sb);
  v.w = xv.w + mishf(v.w * sw + sb);
  *reinterpret_cast<float4*>(y + i) = v;
}

extern "C" void kernel_launch(void* const* d_in, const int* in_sizes, int n_in,
                              void* d_out, int out_size, void* d_ws, size_t ws_size,
                              hipStream_t stream) {
  const float* x     = (const float*)d_in[0];
  const float* gn_w  = (const float*)d_in[1];
  const float* gn_b  = (const float*)d_in[2];
  const float* wqkv  = (const float*)d_in[3];
  const float* bqkv  = (const float*)d_in[4];
  const float* gnq_w = (const float*)d_in[5];
  const float* gnq_b = (const float*)d_in[6];
  const float* wproj = (const float*)d_in[7];
  const float* bproj = (const float*)d_in[8];
  const float* gnp_w = (const float*)d_in[9];
  const float* gnp_b = (const float*)d_in[10];
  float* out = (float*)d_out;

  char* ws = (char*)d_ws;
  const size_t MB = 1024 * 1024;
  // Time-multiplexed workspace (<= 64MB):
  __hip_bfloat16* qkvb = (__hip_bfloat16*)ws;            // [0,24MB)   step4 -> step5
  float* hbuf = (float*)ws;                              // [0,16MB)   step6 -> step7 (qkvb dead)
  __hip_bfloat16* B4t = (__hip_bfloat16*)(ws + 24 * MB); // [24,56MB)  step7 -> step9
  __hip_bfloat16* A1  = (__hip_bfloat16*)(ws + 56 * MB); // [56,59MB)  step2 -> step4
  char* vimg = ws + 56 * MB;                             // [56,64MB)  step5 -> step6 (A1 dead)
  __hip_bfloat16* A2  = (__hip_bfloat16*)(ws + 56 * MB); // [56,58MB)  step8 -> step9 (vimg dead)
  float* st2raw = (float*)(ws + 64 * MB);                // 128 floats
  float* st3raw = st2raw + 128;                          // 128 floats
  __hip_bfloat16* B1t = (__hip_bfloat16*)d_out;          // d_out as B1t  step3 -> step4
  char* qTp  = (char*)d_out;                             // d_out[0,8MB)  step5 -> step6
  char* kimg = (char*)d_out + 8 * MB;                    // d_out[8,16MB) step5 -> step6

  dim3 blk(256);
  zero_stats<<<1, blk, 0, stream>>>(st2raw);                                       // 1 (zeros both)
  cast_bf16<<<1536, blk, 0, stream>>>(wqkv, A1, C3 * 1024);                        // 2
  gn1_im2col<<<256, blk, 0, stream>>>(x, gn_w, gn_b, B1t);                         // 3
  gemm_bt4<1024, 12, 8, 192, 8, true><<<768, blk, 0, stream>>>(A1, B1t, bqkv, qkvb, st2raw);   // 4
  gn2_prep<<<1024, blk, 0, stream>>>(qkvb, st2raw, gnq_w, gnq_b, qTp, kimg, vimg); // 5
  attn_mfma2<<<dim3(16, 64), blk, 0, stream>>>(qTp, kimg, vimg, hbuf);             // 6
  im2col_k4<<<256, blk, 0, stream>>>(hbuf, B4t);                                   // 7
  cast_bf16<<<1024, blk, 0, stream>>>(wproj, A2, Cc * 2048);                       // 8
  gemm_bt4<2048, 4, 8, 64, 8, false><<<256, blk, 0, stream>>>(A2, B4t, bproj, out, st3raw);    // 9
  final_kernel<<<4096, blk, 0, stream>>>(x, out, st3raw, gnp_w, gnp_b);            // 10
}

// Round 8
// 280.256 us; speedup vs baseline: 1.3105x; 1.2248x over previous
//
#include <hip/hip_runtime.h>
#include <hip/hip_bf16.h>
#include <math.h>

#define TID threadIdx.x

constexpr int Cc = 512, Tt = 1024, C3 = 1536;

typedef __attribute__((ext_vector_type(8))) __bf16 bf16x8;
typedef __attribute__((ext_vector_type(4))) float f32x4;

__device__ __forceinline__ void async16(const void* g, void* l) {
  __builtin_amdgcn_global_load_lds(
      (const __attribute__((address_space(1))) unsigned int*)g,
      (__attribute__((address_space(3))) unsigned int*)l, 16, 0, 0);
}

__device__ __forceinline__ unsigned int pack2bf(float a, float b) {
  __hip_bfloat162 h;
  h.x = __float2bfloat16(a);
  h.y = __float2bfloat16(b);
  return *reinterpret_cast<unsigned int*>(&h);
}

__device__ __forceinline__ float bf2f(unsigned short u) {
  unsigned int t = ((unsigned int)u) << 16;
  union { unsigned int i; float f; } c;
  c.i = t;
  return c.f;
}

__device__ __forceinline__ float mishf(float x) {
  float sp = (x > 20.f) ? x : log1pf(__expf(x));
  return x * tanhf(sp);
}

__device__ __forceinline__ void blockReduce2(float& s, float& ss) {
  #pragma unroll
  for (int off = 32; off > 0; off >>= 1) {
    s  += __shfl_xor(s,  off);
    ss += __shfl_xor(ss, off);
  }
  __shared__ float ls[4], lss[4];
  int w = TID >> 6;
  if ((TID & 63) == 0) { ls[w] = s; lss[w] = ss; }
  __syncthreads();
  s  = ls[0] + ls[1] + ls[2] + ls[3];
  ss = lss[0] + lss[1] + lss[2] + lss[3];
}

// ---------------- zero the raw-stat accumulators (256 floats) ----------------
__global__ void zero_stats(float* p) { p[TID] = 0.f; }

// ---------------- fused GN(32) + im2col(K=2, pad_lo=0) -> bf16 B1t[b][t][k=2ci+j] ----------------
__global__ __launch_bounds__(256) void gn1_im2col(const float* __restrict__ x,
    const float* __restrict__ w, const float* __restrict__ bv,
    __hip_bfloat16* __restrict__ B1t) {
  __shared__ float hs[16][262];
  int blk = blockIdx.x, bb = blk >> 5, g = blk & 31;
  size_t base = ((size_t)bb * Cc + g * 16) * Tt;
  const float* xp = x + base;
  float s = 0.f, ss = 0.f;
  for (int i = TID * 4; i < 16 * Tt; i += 1024) {
    float4 v = *reinterpret_cast<const float4*>(xp + i);
    s  += v.x + v.y + v.z + v.w;
    ss += v.x * v.x + v.y * v.y + v.z * v.z + v.w * v.w;
  }
  blockReduce2(s, ss);
  float mean = s * (1.f / 16384.f);
  float rstd = rsqrtf(ss * (1.f / 16384.f) - mean * mean + 1e-5f);

  char* ob = reinterpret_cast<char*>(B1t + (size_t)bb * Tt * 1024 + g * 32);
  for (int tc = 0; tc < 4; ++tc) {
    int tbase = tc * 256;
    __syncthreads();
    for (int task = TID; task < 1024; task += 256) {
      int row = task >> 6, c4 = task & 63;
      int ch = g * 16 + row;
      float sw = w[ch] * rstd;
      float sb = bv[ch] - mean * sw;
      float4 v = *reinterpret_cast<const float4*>(xp + (size_t)row * Tt + tbase + c4 * 4);
      hs[row][c4 * 4 + 0] = v.x * sw + sb;
      hs[row][c4 * 4 + 1] = v.y * sw + sb;
      hs[row][c4 * 4 + 2] = v.z * sw + sb;
      hs[row][c4 * 4 + 3] = v.w * sw + sb;
    }
    if (TID < 16) {
      int row = TID, t = tbase + 256;
      float val = 0.f;
      if (t < Tt) {
        int ch = g * 16 + row;
        float sw = w[ch] * rstd;
        float sb = bv[ch] - mean * sw;
        val = xp[(size_t)row * Tt + t] * sw + sb;
      }
      hs[row][256] = val;
    }
    __syncthreads();
    for (int task = TID; task < 1024; task += 256) {
      int t = task >> 2, cj = task & 3;
      int ci = cj * 4;
      uint4 u;
      u.x = pack2bf(hs[ci + 0][t], hs[ci + 0][t + 1]);
      u.y = pack2bf(hs[ci + 1][t], hs[ci + 1][t + 1]);
      u.z = pack2bf(hs[ci + 2][t], hs[ci + 2][t + 1]);
      u.w = pack2bf(hs[ci + 3][t], hs[ci + 3][t + 1]);
      *reinterpret_cast<uint4*>(ob + ((size_t)(tbase + t) * 1024 + cj * 8) * 2) = u;
    }
  }
}

// ---------------- im2col(K=4, pad_lo=1) on attn output -> bf16 B4t[b][t][k=4ci+j], coalesced ----------------
__global__ __launch_bounds__(256) void im2col_k4(const float* __restrict__ a,
    __hip_bfloat16* __restrict__ B4t) {
  __shared__ float hs[16][266];
  int bb = blockIdx.x >> 5, cg = blockIdx.x & 31;
  const float* ab = a + ((size_t)bb * Cc + cg * 16) * Tt;
  char* ob = reinterpret_cast<char*>(B4t + (size_t)bb * Tt * 2048 + cg * 64);
  for (int tc = 0; tc < 4; ++tc) {
    int tbase = tc * 256;
    __syncthreads();
    for (int task = TID; task < 1024; task += 256) {
      int row = task >> 6, c4 = task & 63;
      float4 v = *reinterpret_cast<const float4*>(ab + (size_t)row * Tt + tbase + c4 * 4);
      hs[row][c4 * 4 + 1] = v.x;
      hs[row][c4 * 4 + 2] = v.y;
      hs[row][c4 * 4 + 3] = v.z;
      hs[row][c4 * 4 + 4] = v.w;
    }
    if (TID < 48) {
      int row = TID / 3, e = TID % 3;
      int t = (e == 0) ? tbase - 1 : tbase + 256 + (e - 1);
      float v = (t >= 0 && t < Tt) ? ab[(size_t)row * Tt + t] : 0.f;
      int col = (e == 0) ? 0 : 257 + (e - 1);
      hs[row][col] = v;
    }
    __syncthreads();
    for (int task = TID; task < 2048; task += 256) {
      int t = task >> 3, cj = task & 7;
      int ci = cj * 2;
      uint4 u;
      u.x = pack2bf(hs[ci][t],     hs[ci][t + 1]);
      u.y = pack2bf(hs[ci][t + 2], hs[ci][t + 3]);
      u.z = pack2bf(hs[ci + 1][t],     hs[ci + 1][t + 1]);
      u.w = pack2bf(hs[ci + 1][t + 2], hs[ci + 1][t + 3]);
      *reinterpret_cast<uint4*>(ob + ((size_t)(tbase + t) * 2048 + cj * 8) * 2) = u;
    }
  }
}

// ---------------- f32 -> bf16 cast (weights) ----------------
__global__ __launch_bounds__(256) void cast_bf16(const float* __restrict__ in,
    __hip_bfloat16* __restrict__ out, int n) {
  int i = (blockIdx.x * 256 + TID) * 4;
  if (i >= n) return;
  float4 v = *reinterpret_cast<const float4*>(in + i);
  *reinterpret_cast<unsigned int*>(out + i)     = pack2bf(v.x, v.y);
  *reinterpret_cast<unsigned int*>(out + i + 2) = pack2bf(v.z, v.w);
}

// ---------------- bf16 MFMA GEMM v5: R4-proven core (BK=64, single 32KB buffer, natural grid)
//                  + fused GN raw-stats (LDS-prereduced, <=4 atomics/block) + optional bf16 out ----
// C[b][o][t] = sum_k A[o][k] * Bt[b][t][k] + bias[o]
template<int K, int MT, int GROWS, int NGRP, bool BF16OUT>
__global__ __launch_bounds__(256) void gemm_bt5(const __hip_bfloat16* __restrict__ A,
    const __hip_bfloat16* __restrict__ Bt, const float* __restrict__ bias,
    void* __restrict__ Cout, float* __restrict__ statraw, int M) {
  constexpr int ACH = (MT / 16) * 2;       // A chunks of 1KB
  constexpr int NCH = ACH + 16;            // + B chunks (128 cols)
  constexpr int NF  = (MT == 128) ? 4 : 2; // n-fragments per wave
  __shared__ __align__(16) char lds[NCH * 1024];
  int t0 = blockIdx.x * 128, o0 = blockIdx.y * MT, bz = blockIdx.z;
  int wave = TID >> 6, lane = TID & 63;
  int l4 = lane >> 4, r15 = lane & 15;
  const __hip_bfloat16* Ab = A + (size_t)o0 * K;
  const __hip_bfloat16* Bb = Bt + ((size_t)bz * 1024 + t0) * K;
  int mbase = (MT == 128) ? (wave >> 1) * 4 : 0;
  int nbase = (MT == 128) ? (wave & 1) * 4 : wave * 2;

  f32x4 acc[4][NF];
  f32x4 zz = {0.f, 0.f, 0.f, 0.f};
  #pragma unroll
  for (int m = 0; m < 4; ++m)
    #pragma unroll
    for (int n = 0; n < NF; ++n) acc[m][n] = zz;

  for (int kt = 0; kt < K / 64; ++kt) {
    #pragma unroll
    for (int c = 0; c < NCH / 4; ++c) {
      int ch = c * 4 + wave;
      int cl = (ch < ACH) ? ch : ch - ACH;
      int row = (cl >> 1) * 16 + r15;
      int kof = kt * 64 + (cl & 1) * 32 + l4 * 8;
      const __hip_bfloat16* src = (ch < ACH) ? (Ab + (size_t)row * K + kof)
                                             : (Bb + (size_t)row * K + kof);
      async16(src, lds + ch * 1024 + lane * 16);
    }
    __syncthreads();
    #pragma unroll
    for (int kk = 0; kk < 2; ++kk) {
      bf16x8 af[4], bfr[NF];
      #pragma unroll
      for (int m = 0; m < 4; ++m)
        af[m] = *reinterpret_cast<const bf16x8*>(lds + ((mbase + m) * 2 + kk) * 1024 + lane * 16);
      #pragma unroll
      for (int n = 0; n < NF; ++n)
        bfr[n] = *reinterpret_cast<const bf16x8*>(lds + (ACH + (nbase + n) * 2 + kk) * 1024 + lane * 16);
      #pragma unroll
      for (int m = 0; m < 4; ++m)
        #pragma unroll
        for (int n = 0; n < NF; ++n)
          acc[m][n] = __builtin_amdgcn_mfma_f32_16x16x32_bf16(af[m], bfr[n], acc[m][n], 0, 0, 0);
    }
    __syncthreads();
  }

  // epilogue: store (+bias); per-(wave,m) lane-reduced stats into LDS, then <=2 groups -> atomics
  float* sred = reinterpret_cast<float*>(lds);  // 32 floats, buffer is dead
  #pragma unroll
  for (int m = 0; m < 4; ++m) {
    float s = 0.f, ss2 = 0.f;
    #pragma unroll
    for (int n = 0; n < NF; ++n) {
      int ocol = t0 + (nbase + n) * 16 + r15;
      #pragma unroll
      for (int r = 0; r < 4; ++r) {
        int orow = o0 + (mbase + m) * 16 + l4 * 4 + r;
        float v = acc[m][n][r] + bias[orow];
        if constexpr (BF16OUT)
          ((__hip_bfloat16*)Cout)[((size_t)bz * M + orow) * 1024 + ocol] = __float2bfloat16(v);
        else
          ((float*)Cout)[((size_t)bz * M + orow) * 1024 + ocol] = v;
        s += v;
        ss2 += v * v;
      }
    }
    #pragma unroll
    for (int off = 1; off < 64; off <<= 1) {
      s   += __shfl_xor(s, off);
      ss2 += __shfl_xor(ss2, off);
    }
    if (lane == 0) {
      sred[(wave * 4 + m) * 2]     = s;
      sred[(wave * 4 + m) * 2 + 1] = ss2;
    }
  }
  __syncthreads();
  if (TID < 2) {
    int g0 = o0 / GROWS;
    int gl = TID;
    float S = 0.f, SS = 0.f;
    int cnt = 0;
    #pragma unroll
    for (int slot = 0; slot < 16; ++slot) {
      int stripe = ((MT == 128) ? ((slot >> 3) << 2) : 0) + (slot & 3);
      int g = (o0 + stripe * 16) / GROWS;
      if (g == g0 + gl) {
        S  += sred[slot * 2];
        SS += sred[slot * 2 + 1];
        ++cnt;
      }
    }
    if (cnt) {
      atomicAdd(&statraw[2 * (bz * NGRP + g0 + gl)],     S);
      atomicAdd(&statraw[2 * (bz * NGRP + g0 + gl) + 1], SS);
    }
  }
}

// ---------------- fused GN(8)+Mish + build attn input images (bf16 qkv input, raw stats) ----------------
__global__ __launch_bounds__(256) void gn2_prep(const __hip_bfloat16* __restrict__ qkv,
    const float* __restrict__ straw, const float* __restrict__ w, const float* __restrict__ bv,
    char* __restrict__ qTp, char* __restrict__ kimg, char* __restrict__ vimg) {
  __shared__ unsigned short hbf[192 * 66];
  int tl = blockIdx.x & 15, hb = blockIdx.x >> 4;
  int b = hb >> 3, hd = hb & 7;
  float rs = straw[2 * (b * 8 + hd)], rq = straw[2 * (b * 8 + hd) + 1];
  float mean = rs * (1.f / 196608.f);
  float rstd = rsqrtf(fmaxf(rq * (1.f / 196608.f) - mean * mean, 0.f) + 1e-5f);
  for (int task = TID; task < 768; task += 256) {
    int row = task >> 2, seg = task & 3;
    int ch = hd * 192 + row;
    float sw = w[ch] * rstd;
    float sb = bv[ch] - mean * sw;
    const uint4* src = reinterpret_cast<const uint4*>(
        qkv + ((size_t)(b * C3 + ch)) * 1024 + tl * 64 + seg * 16);
    uint4 u0 = src[0], u1 = src[1];
    unsigned int uu[8] = {u0.x, u0.y, u0.z, u0.w, u1.x, u1.y, u1.z, u1.w};
    unsigned int* dst = reinterpret_cast<unsigned int*>(&hbf[row * 66 + seg * 16]);
    #pragma unroll
    for (int j = 0; j < 8; ++j) {
      float a = mishf(bf2f((unsigned short)(uu[j] & 0xffff)) * sw + sb);
      float c = mishf(bf2f((unsigned short)(uu[j] >> 16)) * sw + sb);
      dst[j] = pack2bf(a, c);
    }
  }
  __syncthreads();
  size_t tileof = ((size_t)hb * 16 + tl) * 8192;
  {
    int t = TID & 63, sel = TID >> 6;
    int img = sel >> 1, half = sel & 1;
    char* obase = (img == 0 ? qTp : kimg) + tileof + (size_t)t * 128;
    #pragma unroll
    for (int cc = 0; cc < 4; ++cc) {
      int chunk = half * 4 + cc;
      uint4 u;
      unsigned int* up = reinterpret_cast<unsigned int*>(&u);
      #pragma unroll
      for (int j = 0; j < 4; ++j) {
        int c = chunk * 8 + j * 2;
        unsigned int lo = hbf[(img * 64 + c) * 66 + t];
        unsigned int hi = hbf[(img * 64 + c + 1) * 66 + t];
        up[j] = lo | (hi << 16);
      }
      int cpos = (img == 0) ? chunk : (chunk ^ (t & 7));
      *reinterpret_cast<uint4*>(obase + cpos * 16) = u;
    }
  }
  {
    int c = TID & 63, qtr = TID >> 6;
    const unsigned int* vrow = reinterpret_cast<const unsigned int*>(&hbf[(128 + c) * 66]);
    char* obase = vimg + tileof + (size_t)c * 128;
    #pragma unroll
    for (int k = 0; k < 2; ++k) {
      int chunk = qtr * 2 + k;
      uint4 u;
      unsigned int* up = reinterpret_cast<unsigned int*>(&u);
      #pragma unroll
      for (int j = 0; j < 4; ++j) up[j] = vrow[chunk * 4 + j];
      *reinterpret_cast<uint4*>(obase + (chunk ^ (c & 7)) * 16) = u;
    }
  }
}

// ---------------- MFMA flash attention v2: async-staged images, double-buffered ----------------
__global__ __launch_bounds__(256) void attn_mfma2(const char* __restrict__ qTp,
    const char* __restrict__ kimg, const char* __restrict__ vimg,
    float* __restrict__ a) {
  __shared__ __align__(16) char smem[40960];
  char* kbuf0 = smem;
  char* kbuf1 = smem + 8192;
  char* vbuf0 = smem + 16384;
  char* vbuf1 = smem + 24576;
  char* pp    = smem + 32768;
  char* ov    = smem;

  int tl = blockIdx.x, hb = blockIdx.y;
  int b = hb >> 3, hd = hb & 7;
  int lane = TID & 63, wave = TID >> 6;
  int l4 = lane >> 4, r15 = lane & 15;
  size_t ibase = (size_t)hb * 16 * 8192;
  const char* ksrc = kimg + ibase;
  const char* vsrc = vimg + ibase;

  #pragma unroll
  for (int j = 0; j < 2; ++j) {
    int u = j * 256 + TID;
    async16(ksrc + u * 16, kbuf0 + u * 16);
    async16(vsrc + u * 16, vbuf0 + u * 16);
  }
  bf16x8 aq[2];
  int tg = wave * 16 + r15;
  const char* qrow = qTp + ibase + (size_t)tl * 8192 + (size_t)tg * 128;
  aq[0] = *reinterpret_cast<const bf16x8*>(qrow + l4 * 16);
  aq[1] = *reinterpret_cast<const bf16x8*>(qrow + 64 + l4 * 16);

  f32x4 osum[4];
  f32x4 zz = {0.f, 0.f, 0.f, 0.f};
  #pragma unroll
  for (int cf = 0; cf < 4; ++cf) osum[cf] = zz;
  float mrow[4] = {-1e30f, -1e30f, -1e30f, -1e30f};
  float lrow[4] = {0.f, 0.f, 0.f, 0.f};
  __syncthreads();

  for (int it = 0; it < 16; ++it) {
    char* kcur = (it & 1) ? kbuf1 : kbuf0;
    char* vcur = (it & 1) ? vbuf1 : vbuf0;
    if (it < 15) {
      char* knxt = (it & 1) ? kbuf0 : kbuf1;
      char* vnxt = (it & 1) ? vbuf0 : vbuf1;
      const char* kn = ksrc + (size_t)(it + 1) * 8192;
      const char* vn = vsrc + (size_t)(it + 1) * 8192;
      #pragma unroll
      for (int j = 0; j < 2; ++j) {
        int u = j * 256 + TID;
        async16(kn + u * 16, knxt + u * 16);
        async16(vn + u * 16, vnxt + u * 16);
      }
    }
    f32x4 sc[4];
    #pragma unroll
    for (int sf = 0; sf < 4; ++sf) sc[sf] = zz;
    #pragma unroll
    for (int sf = 0; sf < 4; ++sf) {
      int sr = sf * 16 + r15;
      #pragma unroll
      for (int kk = 0; kk < 2; ++kk) {
        bf16x8 bk = *reinterpret_cast<const bf16x8*>(kcur + sr * 128 + (((kk * 4 + l4) ^ (sr & 7)) << 4));
        sc[sf] = __builtin_amdgcn_mfma_f32_16x16x32_bf16(aq[kk], bk, sc[sf], 0, 0, 0);
      }
    }
    float tmax[4];
    #pragma unroll
    for (int r = 0; r < 4; ++r)
      tmax[r] = fmaxf(fmaxf(sc[0][r], sc[1][r]), fmaxf(sc[2][r], sc[3][r]));
    #pragma unroll
    for (int off = 1; off < 16; off <<= 1)
      #pragma unroll
      for (int r = 0; r < 4; ++r) tmax[r] = fmaxf(tmax[r], __shfl_xor(tmax[r], off));
    float alpha[4];
    #pragma unroll
    for (int r = 0; r < 4; ++r) {
      float mnew = fmaxf(mrow[r], tmax[r]);
      alpha[r] = __expf((mrow[r] - mnew) * 0.125f);
      mrow[r] = mnew;
      lrow[r] *= alpha[r];
    }
    #pragma unroll
    for (int cf = 0; cf < 4; ++cf)
      #pragma unroll
      for (int r = 0; r < 4; ++r) osum[cf][r] *= alpha[r];
    char* pw = pp + wave * 2048;
    float psum[4] = {0.f, 0.f, 0.f, 0.f};
    #pragma unroll
    for (int sf = 0; sf < 4; ++sf) {
      int s = sf * 16 + r15;
      #pragma unroll
      for (int r = 0; r < 4; ++r) {
        float p = __expf((sc[sf][r] - mrow[r]) * 0.125f);
        psum[r] += p;
        int tlc = l4 * 4 + r;
        *reinterpret_cast<__hip_bfloat16*>(pw + tlc * 128 + ((((s >> 3) ^ (tlc & 7)) << 4) | ((s & 7) * 2)))
            = __float2bfloat16(p);
      }
    }
    #pragma unroll
    for (int r = 0; r < 4; ++r) lrow[r] += psum[r];
    asm volatile("s_waitcnt lgkmcnt(0)" ::: "memory");
    __builtin_amdgcn_sched_barrier(0);

    bf16x8 pa[2];
    #pragma unroll
    for (int kk = 0; kk < 2; ++kk)
      pa[kk] = *reinterpret_cast<const bf16x8*>(pw + r15 * 128 + (((kk * 4 + l4) ^ (r15 & 7)) << 4));
    #pragma unroll
    for (int cf = 0; cf < 4; ++cf) {
      int cr = cf * 16 + r15;
      #pragma unroll
      for (int kk = 0; kk < 2; ++kk) {
        bf16x8 bv = *reinterpret_cast<const bf16x8*>(vcur + cr * 128 + (((kk * 4 + l4) ^ (cr & 7)) << 4));
        osum[cf] = __builtin_amdgcn_mfma_f32_16x16x32_bf16(pa[kk], bv, osum[cf], 0, 0, 0);
      }
    }
    __syncthreads();
  }

  #pragma unroll
  for (int off = 1; off < 16; off <<= 1)
    #pragma unroll
    for (int r = 0; r < 4; ++r) lrow[r] += __shfl_xor(lrow[r], off);
  float linv[4];
  #pragma unroll
  for (int r = 0; r < 4; ++r) linv[r] = 1.f / lrow[r];

  #pragma unroll
  for (int cf = 0; cf < 4; ++cf) {
    int c = cf * 16 + r15;
    #pragma unroll
    for (int r = 0; r < 4; ++r) {
      int t = wave * 16 + l4 * 4 + r;
      *reinterpret_cast<float*>(ov + c * 256 + ((((t >> 2) ^ (c & 7)) << 4) | ((t & 3) * 4)))
          = osum[cf][r] * linv[r];
    }
  }
  __syncthreads();
  float* ap = a + ((size_t)b * Cc + hd * 64) * Tt + tl * 64;
  for (int u = TID; u < 1024; u += 256) {
    int c = u >> 4, tq = u & 15;
    float4 o4 = *reinterpret_cast<const float4*>(ov + c * 256 + ((tq ^ (c & 7)) << 4));
    *reinterpret_cast<float4*>(ap + (size_t)c * Tt + tq * 4) = o4;
  }
}

// ---------------- final: out = x + mish(gn(y2)) in-place on d_out (raw stats) ----------------
__global__ __launch_bounds__(256) void final_kernel(const float* __restrict__ x,
    float* __restrict__ y, const float* __restrict__ straw,
    const float* __restrict__ w, const float* __restrict__ bv) {
  size_t i = ((size_t)blockIdx.x * 256 + TID) * 4;
  int ch = (int)((i >> 10) & (Cc - 1));
  int b = (int)(i >> 19);
  int g = b * 8 + (ch >> 6);
  float rs = straw[2 * g], rq = straw[2 * g + 1];
  float mean = rs * (1.f / 65536.f);
  float rstd = rsqrtf(fmaxf(rq * (1.f / 65536.f) - mean * mean, 0.f) + 1e-5f);
  float sw = w[ch] * rstd;
  float sb = bv[ch] - mean * sw;
  float4 v  = *reinterpret_cast<const float4*>(y + i);
  float4 xv = *reinterpret_cast<const float4*>(x + i);
  v.x = xv.x + mishf(v.x * sw + sb);
  v.y = xv.y + mishf(v.y * sw + sb);
  v.z = xv.z + mishf(v.z * sw + sb);
  v.w = xv.w + mishf(v.w * sw + sb);
  *reinterpret_cast<float4*>(y + i) = v;
}

extern "C" void kernel_launch(void* const* d_in, const int* in_sizes, int n_in,
                              void* d_out, int out_size, void* d_ws, size_t ws_size,
                              hipStream_t stream) {
  const float* x     = (const float*)d_in[0];
  const float* gn_w  = (const float*)d_in[1];
  const float* gn_b  = (const float*)d_in[2];
  const float* wqkv  = (const float*)d_in[3];
  const float* bqkv  = (const float*)d_in[4];
  const float* gnq_w = (const float*)d_in[5];
  const float* gnq_b = (const float*)d_in[6];
  const float* wproj = (const float*)d_in[7];
  const float* bproj = (const float*)d_in[8];
  const float* gnp_w = (const float*)d_in[9];
  const float* gnp_b = (const float*)d_in[10];
  float* out = (float*)d_out;

  char* ws = (char*)d_ws;
  const size_t MB = 1024 * 1024;
  // Time-multiplexed workspace (<= 64MB):
  __hip_bfloat16* qkvb = (__hip_bfloat16*)ws;            // [0,24MB)   step4 -> step5
  float* hbuf = (float*)ws;                              // [0,16MB)   step6 -> step7 (qkvb dead)
  __hip_bfloat16* B4t = (__hip_bfloat16*)(ws + 24 * MB); // [24,56MB)  step7 -> step9
  __hip_bfloat16* A1  = (__hip_bfloat16*)(ws + 56 * MB); // [56,59MB)  step2 -> step4
  char* vimg = ws + 56 * MB;                             // [56,64MB)  step5 -> step6 (A1 dead)
  __hip_bfloat16* A2  = (__hip_bfloat16*)(ws + 56 * MB); // [56,58MB)  step8 -> step9 (vimg dead)
  float* st2raw = (float*)(ws + 64 * MB);                // 128 floats
  float* st3raw = st2raw + 128;                          // 128 floats
  __hip_bfloat16* B1t = (__hip_bfloat16*)d_out;          // d_out as B1t  step3 -> step4
  char* qTp  = (char*)d_out;                             // d_out[0,8MB)  step5 -> step6
  char* kimg = (char*)d_out + 8 * MB;                    // d_out[8,16MB) step5 -> step6

  dim3 blk(256);
  zero_stats<<<1, blk, 0, stream>>>(st2raw);                                       // 1 (zeros both)
  cast_bf16<<<1536, blk, 0, stream>>>(wqkv, A1, C3 * 1024);                        // 2
  gn1_im2col<<<256, blk, 0, stream>>>(x, gn_w, gn_b, B1t);                         // 3
  gemm_bt5<1024, 128, 192, 8, true><<<dim3(8, 12, 8), blk, 0, stream>>>(
      A1, B1t, bqkv, qkvb, st2raw, C3);                                            // 4
  gn2_prep<<<1024, blk, 0, stream>>>(qkvb, st2raw, gnq_w, gnq_b, qTp, kimg, vimg); // 5
  attn_mfma2<<<dim3(16, 64), blk, 0, stream>>>(qTp, kimg, vimg, hbuf);             // 6
  im2col_k4<<<256, blk, 0, stream>>>(hbuf, B4t);                                   // 7
  cast_bf16<<<1024, blk, 0, stream>>>(wproj, A2, Cc * 2048);                       // 8
  gemm_bt5<2048, 64, 64, 8, false><<<dim3(8, 8, 8), blk, 0, stream>>>(
      A2, B4t, bproj, out, st3raw, Cc);                                            // 9
  final_kernel<<<4096, blk, 0, stream>>>(x, out, st3raw, gnp_w, gnp_b);            // 10
}